// Round 3
// baseline (214.834 us; speedup 1.0000x reference)
//
#include <hip/hip_runtime.h>
#include <cstdint>

typedef unsigned short u16;
typedef __attribute__((ext_vector_type(8))) short short8;
typedef __attribute__((ext_vector_type(4))) short short4v;
typedef __attribute__((ext_vector_type(4))) float f32x4;
typedef __attribute__((ext_vector_type(4))) unsigned short u16x4;

__device__ __forceinline__ u16 f2bf(float x) {
    unsigned int u = __float_as_uint(x);
    u += 0x7fffu + ((u >> 16) & 1u);
    return (u16)(u >> 16);
}

__device__ __forceinline__ float fexp2(float x) {
#if __has_builtin(__builtin_amdgcn_exp2f)
    return __builtin_amdgcn_exp2f(x);
#else
    return exp2f(x);
#endif
}

// pack two rounded f32 -> bf16 pair in one dword (a low16, b high16) — proven path
__device__ __forceinline__ unsigned pack_bf16(float a, float b) {
    unsigned ua = __float_as_uint(a) + 0x8000u;
    unsigned ub = __float_as_uint(b) + 0x8000u;
    return __builtin_amdgcn_perm(ub, ua, 0x07060302u);
}

#if __has_builtin(__builtin_amdgcn_mfma_f32_16x16x16bf16_1k)
__device__ __forceinline__ f32x4 mfma16(short4v a, short4v b, f32x4 c) {
    return __builtin_amdgcn_mfma_f32_16x16x16bf16_1k(a, b, c, 0, 0, 0);
}
#else
__device__ __forceinline__ f32x4 mfma16(short4v a, short4v b, f32x4 c) {
    short8 a8 = {a[0], a[1], a[2], a[3], 0, 0, 0, 0};
    short8 b8 = {b[0], b[1], b[2], b[3], 0, 0, 0, 0};
    return __builtin_amdgcn_mfma_f32_16x16x32_bf16(a8, b8, c, 0, 0, 0);
}
#endif

__device__ __forceinline__ void gload_lds16(const u16* g, u16* l) {
    __builtin_amdgcn_global_load_lds(
        (const __attribute__((address_space(1))) void*)(g),
        (__attribute__((address_space(3))) void*)(l),
        16, 0, 0);
}

// ---------------- fused prep: Wo transpose | cast x | Wq/Wk/Wv transposes ------
// grid = (16, 16, 5): z=0 Wo (x,y tile); z=1 cast x (flat 256 blocks);
// z=2..4 W{q,k,v}: y = head, x = 64-row tile of d.
__global__ __launch_bounds__(256) void prep_kernel(
    const float* __restrict__ x,
    const float* __restrict__ Wq, const float* __restrict__ Wk,
    const float* __restrict__ Wv, const float* __restrict__ Wo,
    u16* __restrict__ xb, u16* __restrict__ wqkv, u16* __restrict__ wot)
{
    __shared__ u16 tile[64][65];
    const int z = blockIdx.z;
    const int tc = threadIdx.x & 63, tr = threadIdx.x >> 6;

    if (z == 1) {
        // cast x: 4,194,304 f32 -> bf16; 256 blocks x 256 thr x 16 float4
        const int blk = blockIdx.y * 16 + blockIdx.x;
        const int base = (blk * 256 + threadIdx.x) * 4;
        #pragma unroll
        for (int i = 0; i < 16; ++i) {
            const int idx = base + i * 262144;
            float4 v = *(const float4*)(x + idx);
            u16x4 o;
            o.x = f2bf(v.x); o.y = f2bf(v.y); o.z = f2bf(v.z); o.w = f2bf(v.w);
            *(u16x4*)(xb + idx) = o;
        }
        return;
    }

    const float* src;
    u16* dst;
    int C, R, rb, cb;
    if (z == 0) {
        src = Wo; dst = wot; C = 1024; R = 1024;
        rb = blockIdx.x * 64; cb = blockIdx.y * 64;
    } else {
        const float* W = (z == 2) ? Wq : (z == 3) ? Wk : Wv;
        const int head = blockIdx.y;
        src = W + head * 65536;                                  // [1024][64]
        dst = wqkv + (size_t)(z - 2) * 1048576 + head * 65536;   // rows e, cols d
        C = 64; R = 1024;
        rb = blockIdx.x * 64; cb = 0;
    }
    #pragma unroll
    for (int i = 0; i < 64; i += 4)
        tile[tr + i][tc] = f2bf(src[(size_t)(rb + tr + i) * C + (cb + tc)]);
    __syncthreads();
    #pragma unroll
    for (int i = 0; i < 64; i += 4)
        dst[(size_t)(cb + tr + i) * R + (rb + tc)] = tile[tc][tr + i];
}

// ---------------- QKV GEMM: [4096,1024] x [3072,1024]^T ----------------
// grid (24 n-tiles, 32 m-tiles): consecutive dispatches share the X tile -> L2 reuse.
// __launch_bounds__(256,3): cap unified VGPR+AGPR so 3 blocks/CU are resident.
// Epilogue: +bias; Q*0.125*log2e -> q[bh][s][64]; K -> k[bh][t][64];
//           V -> V2[bh][s/16][e=64][s%16]  (16-key-tiled transpose)
__global__ __launch_bounds__(256, 3) void gemm_qkv_kernel(
    const u16* __restrict__ X, const u16* __restrict__ W,
    const float* __restrict__ bq, const float* __restrict__ bk,
    const float* __restrict__ bv,
    u16* __restrict__ qo, u16* __restrict__ ko, u16* __restrict__ vto)
{
    __shared__ __align__(16) u16 As[128 * 32];
    __shared__ __align__(16) u16 Bs[128 * 32];
    const int tid = threadIdx.x;
    const int lane = tid & 63;
    const int wv = tid >> 6;
    const int wm = wv & 1, wn = wv >> 1;
    const int m0 = blockIdx.y * 128;
    const int n0 = blockIdx.x * 128;
    const int c = lane & 15, qd = lane >> 4;

    f32x4 acc[4][4];
    #pragma unroll
    for (int a = 0; a < 4; ++a)
        #pragma unroll
        for (int b2 = 0; b2 < 4; ++b2) acc[a][b2] = f32x4{0.f, 0.f, 0.f, 0.f};

    const u16* Xb = X + (size_t)m0 * 1024;
    const u16* Wb = W + (size_t)n0 * 1024;

    for (int kt = 0; kt < 1024; kt += 32) {
        #pragma unroll
        for (int i = 0; i < 2; ++i) {
            int slot = i * 256 + tid;
            int row = slot >> 2, part = slot & 3;
            gload_lds16(Xb + (size_t)row * 1024 + kt + part * 8, &As[slot * 8]);
            gload_lds16(Wb + (size_t)row * 1024 + kt + part * 8, &Bs[slot * 8]);
        }
        __syncthreads();
        short8 af[4], bf[4];
        #pragma unroll
        for (int mt = 0; mt < 4; ++mt)
            af[mt] = *(const short8*)&As[(wm * 64 + mt * 16 + c) * 32 + qd * 8];
        #pragma unroll
        for (int nt = 0; nt < 4; ++nt)
            bf[nt] = *(const short8*)&Bs[(wn * 64 + nt * 16 + c) * 32 + qd * 8];
        #pragma unroll
        for (int mt = 0; mt < 4; ++mt)
            #pragma unroll
            for (int nt = 0; nt < 4; ++nt)
                acc[mt][nt] = __builtin_amdgcn_mfma_f32_16x16x32_bf16(af[mt], bf[nt], acc[mt][nt], 0, 0, 0);
        __syncthreads();
    }

    // epilogue: n -> (mat, h, e); m -> (b, s)
    #pragma unroll
    for (int mt = 0; mt < 4; ++mt) {
        const int mbase = m0 + wm * 64 + mt * 16 + qd * 4;
        const int b = mbase >> 11;
        #pragma unroll
        for (int nt = 0; nt < 4; ++nt) {
            const int n = n0 + wn * 64 + nt * 16 + c;
            const int mat = n >> 10;
            const int idx = n & 1023;
            const int h = idx >> 6, e = idx & 63;
            const float bias = (mat == 0 ? bq : (mat == 1 ? bk : bv))[idx];
            if (mat == 2) {
                const int s = mbase & 2047;
                u16x4 pv;
                pv.x = f2bf(acc[mt][nt][0] + bias);
                pv.y = f2bf(acc[mt][nt][1] + bias);
                pv.z = f2bf(acc[mt][nt][2] + bias);
                pv.w = f2bf(acc[mt][nt][3] + bias);
                *(u16x4*)(vto + ((((size_t)(b * 16 + h) * 128 + (s >> 4)) * 64 + e) * 16
                                 + (s & 15))) = pv;
            } else {
                const float scale = (mat == 0) ? 0.18033688011112042f : 1.0f;
                u16* dst = (mat == 0) ? qo : ko;
                #pragma unroll
                for (int r = 0; r < 4; ++r) {
                    const int s = (mbase + r) & 2047;
                    dst[((size_t)((b * 16 + h) * 2048 + s)) * 64 + e] =
                        f2bf((acc[mt][nt][r] + bias) * scale);
                }
            }
        }
    }
}

// ---------------- flash attention v9: v8 body + dynamic work-stealing ----------
// R2 post-mortem: removing 6.3M bank-conflict cycles + 4 MFMA/iter changed dur
// by 0.0% -> flash is tail-bound, not issue-bound. 1024 blocks over 768 resident
// slots (3/CU) = phase2 of 256 blocks at 4 waves/CU (~23 us, ~40% of time).
// Fix: grid 768 (exact residency), blocks steal tiles t=atomicAdd from 1024-tile
// pool until empty -> all CUs stay at 12 waves/CU; tail becomes ~half-tile drain.
// K-loop body is byte-identical to the PASSING v8. Steal loop has two barriers
// per tile: grab-sync (before reading sh_t; doubles as pool-reuse fence) and
// end-sync (so no wave can observe a re-written sh_t — all 4 waves of the
// split-K merge must agree on t).
// tcnt == nullptr -> static fallback (grid 1024, t = blockIdx.x), used when
// ws_size has no room for the counter. Correctness never depends on ws_size.
__global__ __launch_bounds__(256, 3) void flash_kernel(
    const u16* __restrict__ Q,   // [32][2048][64], pre-scaled by 0.125*log2e
    const u16* __restrict__ K,   // [32][2048][64]
    const u16* __restrict__ V2,  // [32][128][64][16]
    u16* __restrict__ ctx,       // [4096][1024] = [b*2048+s][h*64+e]
    unsigned* tcnt)              // steal counter (ws+48MiB) or nullptr
{
    __shared__ __align__(16) char pool[34816];
    __shared__ unsigned sh_t;
    u16* stage = (u16*)pool;                              // K ring-3: 4w*3072 u16 = 24576 B
    float (*Os)[64][66] = (float (*)[64][66])pool;        // merge (aliased): 33792 B
    float (*Ls)[64] = (float (*)[64])(pool + 33792);      // 1 KB (no stage alias)

    const int tid = threadIdx.x, lane = tid & 63, w = tid >> 6;
    const int c = lane & 15, qd = lane >> 4;

    u16* Kst = stage + w * 3072;             // 3 K slots x 1024 u16

    const int krow8 = lane >> 3;                    // row within 8-row group
    const int kgc = (lane & 7) ^ (krow8 & 7);       // pre-swizzled source chunk
    const int voff = c * 16 + qd * 4;               // per-lane V fragment offset

    for (;;) {
        if (tid == 0)
            sh_t = tcnt ? atomicAdd(tcnt, 1u) : (unsigned)blockIdx.x;
        __syncthreads();                       // broadcast t; pool-reuse fence
        const unsigned t = sh_t;
        if (t >= 1024u) break;

        const int bh = (int)(t >> 5);          // 0..31
        const int q0 = (int)(t & 31) << 6;     // 0..1984
        const int b = bh >> 4, h = bh & 15;
        const u16* Qh = Q + (size_t)bh * 131072;
        const u16* Kh = K + (size_t)bh * 131072;
        const u16* Vh = V2 + (size_t)bh * 131072;

        short8 qf[4][2];
        #pragma unroll
        for (int qb = 0; qb < 4; ++qb)
            #pragma unroll
            for (int kb = 0; kb < 2; ++kb)
                qf[qb][kb] = *(const short8*)&Qh[(size_t)(q0 + qb * 16 + c) * 64 + kb * 32 + qd * 8];

        f32x4 o[4][4];        // o[mt][qb]: e = mt*16 + qd*4 + r, q = qb*16 + c
        float lsum[4];        // per-lane P row-sum partial (keys qd*4+r per tile)
        #pragma unroll
        for (int mt = 0; mt < 4; ++mt)
            #pragma unroll
            for (int qb = 0; qb < 4; ++qb) o[mt][qb] = f32x4{0.f, 0.f, 0.f, 0.f};
        #pragma unroll
        for (int qb = 0; qb < 4; ++qb) lsum[qb] = 0.f;

        // prologue: K0 -> slot0; V0 -> vA regs; K1 -> slot1
        #pragma unroll
        for (int j = 0; j < 2; ++j) {
            const int row = j * 8 + krow8;
            gload_lds16(Kh + (size_t)(w * 512 + row) * 64 + kgc * 8,
                        Kst + j * 512 + lane * 8);
        }
        short4v vA[4], vB[4];
        {
            const u16* vb = Vh + (size_t)(w * 32) * 1024 + voff;
            #pragma unroll
            for (int mt = 0; mt < 4; ++mt)
                vA[mt] = *(const short4v*)(vb + mt * 256);
        }
        #pragma unroll
        for (int j = 0; j < 2; ++j) {
            const int row = j * 8 + krow8;
            gload_lds16(Kh + (size_t)(w * 512 + 16 + row) * 64 + kgc * 8,
                        Kst + 1024 + j * 512 + lane * 8);
        }

        int cur = 0;
        auto body = [&](int it, short4v (&VC)[4], short4v (&VN)[4]) {
            u16* Kb = Kst + cur * 1024;

            __builtin_amdgcn_s_waitcnt(0xF74);   // vmcnt(4): K(it) staged
            __builtin_amdgcn_sched_barrier(0);

            short8 kf[2];
            #pragma unroll
            for (int kb = 0; kb < 2; ++kb)
                kf[kb] = *(const short8*)&Kb[c * 64 + ((4 * kb + qd) ^ (c & 7)) * 8];

            __builtin_amdgcn_sched_barrier(0);

            // V register prefetch for it+1 (wrap &31: harmless dummy re-read)
            {
                const int itn = (it + 1) & 31;
                const u16* vb = Vh + (size_t)(w * 32 + itn) * 1024 + voff;
                #pragma unroll
                for (int mt = 0; mt < 4; ++mt)
                    VN[mt] = *(const short4v*)(vb + mt * 256);
            }
            // K stage for it+2 into (cur+2)%3
            {
                const int itn = (it + 2) & 31;
                const int t0n = w * 512 + itn * 16;
                const int nslot = (cur >= 1) ? cur - 1 : 2;
                u16* Kn = Kst + nslot * 1024;
                #pragma unroll
                for (int j = 0; j < 2; ++j) {
                    const int row = j * 8 + krow8;
                    gload_lds16(Kh + (size_t)(t0n + row) * 64 + kgc * 8,
                                Kn + j * 512 + lane * 8);
                }
            }

            f32x4 sc[4];
            #pragma unroll
            for (int qb = 0; qb < 4; ++qb) {
                sc[qb] = f32x4{0.f, 0.f, 0.f, 0.f};
                sc[qb] = __builtin_amdgcn_mfma_f32_16x16x32_bf16(kf[0], qf[qb][0], sc[qb], 0, 0, 0);
                sc[qb] = __builtin_amdgcn_mfma_f32_16x16x32_bf16(kf[1], qf[qb][1], sc[qb], 0, 0, 0);
            }

            short4v pb[4];
            #pragma unroll
            for (int qb = 0; qb < 4; ++qb) {
                float p0 = fexp2(sc[qb][0]);
                float p1 = fexp2(sc[qb][1]);
                float p2 = fexp2(sc[qb][2]);
                float p3 = fexp2(sc[qb][3]);
                lsum[qb] += (p0 + p1) + (p2 + p3);
                unsigned d0 = pack_bf16(p0, p1);
                unsigned d1 = pack_bf16(p2, p3);
                union { unsigned u[2]; short4v s; } pu;
                pu.u[0] = d0; pu.u[1] = d1;
                pb[qb] = pu.s;
            }

            #pragma unroll
            for (int qb = 0; qb < 4; ++qb)
                #pragma unroll
                for (int mt = 0; mt < 4; ++mt)
                    o[mt][qb] = mfma16(VC[mt], pb[qb], o[mt][qb]);

            cur = (cur == 2) ? 0 : cur + 1;
        };

        for (int it2 = 0; it2 < 16; ++it2) {
            body(2 * it2, vA, vB);
            body(2 * it2 + 1, vB, vA);
        }

        __builtin_amdgcn_s_waitcnt(0xF70);   // vmcnt(0) before aliasing the pool
        __syncthreads();

        // finish l: fold the 4 qd-groups into a full 512-key wave sum
        #pragma unroll
        for (int qb = 0; qb < 4; ++qb) {
            lsum[qb] += __shfl_xor(lsum[qb], 16, 64);
            lsum[qb] += __shfl_xor(lsum[qb], 32, 64);
        }
        if (qd == 0) {
            #pragma unroll
            for (int qb = 0; qb < 4; ++qb) Ls[w][qb * 16 + c] = lsum[qb];
        }

        if (w >= 2) {
            float (*S)[66] = Os[w - 2];
            #pragma unroll
            for (int mt = 0; mt < 4; ++mt)
                #pragma unroll
                for (int qb = 0; qb < 4; ++qb)
                    #pragma unroll
                    for (int r = 0; r < 4; ++r)
                        S[mt * 16 + qd * 4 + r][qb * 16 + c] = o[mt][qb][r];
        }
        __syncthreads();
        if (w < 2) {
            float (*S)[66] = Os[w];
            #pragma unroll
            for (int mt = 0; mt < 4; ++mt)
                #pragma unroll
                for (int qb = 0; qb < 4; ++qb)
                    #pragma unroll
                    for (int r = 0; r < 4; ++r)
                        o[mt][qb][r] += S[mt * 16 + qd * 4 + r][qb * 16 + c];
        }
        __syncthreads();
        if (w == 1) {
            float (*S)[66] = Os[0];
            #pragma unroll
            for (int mt = 0; mt < 4; ++mt)
                #pragma unroll
                for (int qb = 0; qb < 4; ++qb)
                    #pragma unroll
                    for (int r = 0; r < 4; ++r)
                        S[mt * 16 + qd * 4 + r][qb * 16 + c] = o[mt][qb][r];
        }
        __syncthreads();
        if (w == 0) {
            float (*S)[66] = Os[0];
            float inv[4];
            #pragma unroll
            for (int qb = 0; qb < 4; ++qb) {
                int q = qb * 16 + c;
                float l = (Ls[0][q] + Ls[1][q]) + (Ls[2][q] + Ls[3][q]);
                inv[qb] = __builtin_amdgcn_rcpf(l);
            }
            #pragma unroll
            for (int mt = 0; mt < 4; ++mt)
                #pragma unroll
                for (int qb = 0; qb < 4; ++qb) {
                    u16x4 ov;
                    #pragma unroll
                    for (int r = 0; r < 4; ++r) {
                        float v = (o[mt][qb][r] + S[mt * 16 + qd * 4 + r][qb * 16 + c]) * inv[qb];
                        ((u16*)&ov)[r] = f2bf(v);
                    }
                    *(u16x4*)&ctx[((size_t)(b * 2048 + q0 + qb * 16 + c)) * 1024
                                  + h * 64 + mt * 16 + qd * 4] = ov;
                }
        }

        __syncthreads();   // all waves consumed sh_t before tid0 re-writes it
        if (!tcnt) break;  // static fallback: one tile per block
    }
}

// ---------------- output projection: ctx[4096,1024] x Wo^T + bo, 64x128 tiles ----
__global__ __launch_bounds__(256, 4) void gemm_out_kernel(
    const u16* __restrict__ A, const u16* __restrict__ Wt,
    const float* __restrict__ bo, float* __restrict__ out)
{
    __shared__ __align__(16) u16 As[64 * 32];
    __shared__ __align__(16) u16 Bs[128 * 32];
    const int tid = threadIdx.x;
    const int lane = tid & 63;
    const int wv = tid >> 6;
    const int wm = wv & 1, wn = wv >> 1;
    const int m0 = blockIdx.x * 64;
    const int n0 = blockIdx.y * 128;
    const int c = lane & 15, qd = lane >> 4;

    f32x4 acc[2][4];
    #pragma unroll
    for (int a = 0; a < 2; ++a)
        #pragma unroll
        for (int b2 = 0; b2 < 4; ++b2) acc[a][b2] = f32x4{0.f, 0.f, 0.f, 0.f};

    const u16* Ab = A + (size_t)m0 * 1024;
    const u16* Wb = Wt + (size_t)n0 * 1024;

    for (int kt = 0; kt < 1024; kt += 32) {
        {
            int row = tid >> 2, part = tid & 3;
            gload_lds16(Ab + (size_t)row * 1024 + kt + part * 8, &As[tid * 8]);
        }
        #pragma unroll
        for (int i = 0; i < 2; ++i) {
            int slot = i * 256 + tid;
            int row = slot >> 2, part = slot & 3;
            gload_lds16(Wb + (size_t)row * 1024 + kt + part * 8, &Bs[slot * 8]);
        }
        __syncthreads();
        short8 af[2], bf[4];
        #pragma unroll
        for (int mt = 0; mt < 2; ++mt)
            af[mt] = *(const short8*)&As[(wm * 32 + mt * 16 + c) * 32 + qd * 8];
        #pragma unroll
        for (int nt = 0; nt < 4; ++nt)
            bf[nt] = *(const short8*)&Bs[(wn * 64 + nt * 16 + c) * 32 + qd * 8];
        #pragma unroll
        for (int mt = 0; mt < 2; ++mt)
            #pragma unroll
            for (int nt = 0; nt < 4; ++nt)
                acc[mt][nt] = __builtin_amdgcn_mfma_f32_16x16x32_bf16(af[mt], bf[nt], acc[mt][nt], 0, 0, 0);
        __syncthreads();
    }

    #pragma unroll
    for (int mt = 0; mt < 2; ++mt) {
        const int mbase = m0 + wm * 32 + mt * 16 + qd * 4;
        #pragma unroll
        for (int nt = 0; nt < 4; ++nt) {
            const int n = n0 + wn * 64 + nt * 16 + c;
            const float bias = bo[n];
            #pragma unroll
            for (int r = 0; r < 4; ++r)
                out[(size_t)(mbase + r) * 1024 + n] = acc[mt][nt][r] + bias;
        }
    }
}

extern "C" void kernel_launch(void* const* d_in, const int* in_sizes, int n_in,
                              void* d_out, int out_size, void* d_ws, size_t ws_size,
                              hipStream_t stream) {
    const float* x  = (const float*)d_in[0];
    const float* Wq = (const float*)d_in[1];
    const float* bq = (const float*)d_in[2];
    const float* Wk = (const float*)d_in[3];
    const float* bk = (const float*)d_in[4];
    const float* Wv = (const float*)d_in[5];
    const float* bv = (const float*)d_in[6];
    const float* Wo = (const float*)d_in[7];
    const float* bo = (const float*)d_in[8];
    float* out = (float*)d_out;

    u16* ws    = (u16*)d_ws;
    u16* xb    = ws;                          // 4096*1024
    u16* wqkv  = xb + 4096 * 1024;            // 3072*1024
    u16* wot   = wqkv + 3072 * 1024;          // 1024*1024
    u16* qws   = wot + 1024 * 1024;           // 32*2048*64
    u16* kws   = qws + 4194304;               // 32*2048*64
    u16* v2ws  = kws + 4194304;               // 32*128*64*16
    u16* ctxws = v2ws + 4194304;              // 4096*1024
    // buffers end at byte 50,331,648 (48 MiB); steal counter goes just past.
    const size_t cnt_off = 50331648;
    unsigned* tcnt = (ws_size >= cnt_off + 64)
                   ? (unsigned*)((char*)d_ws + cnt_off) : nullptr;

    prep_kernel<<<dim3(16, 16, 5), 256, 0, stream>>>(x, Wq, Wk, Wv, Wo, xb, wqkv, wot);
    gemm_qkv_kernel<<<dim3(24, 32), 256, 0, stream>>>(xb, wqkv, bq, bk, bv, qws, kws, v2ws);
    if (tcnt) {
        hipMemsetAsync(tcnt, 0, 4, stream);
        flash_kernel<<<768, 256, 0, stream>>>(qws, kws, v2ws, ctxws, tcnt);
    } else {
        flash_kernel<<<1024, 256, 0, stream>>>(qws, kws, v2ws, ctxws, nullptr);
    }
    gemm_out_kernel<<<dim3(64, 8), 256, 0, stream>>>(ctxws, wot, bo, out);
}

// Round 4
// 200.235 us; speedup vs baseline: 1.0729x; 1.0729x over previous
//
#include <hip/hip_runtime.h>
#include <cstdint>

typedef unsigned short u16;
typedef __attribute__((ext_vector_type(8))) short short8;
typedef __attribute__((ext_vector_type(4))) short short4v;
typedef __attribute__((ext_vector_type(4))) float f32x4;
typedef __attribute__((ext_vector_type(4))) unsigned short u16x4;

__device__ __forceinline__ u16 f2bf(float x) {
    unsigned int u = __float_as_uint(x);
    u += 0x7fffu + ((u >> 16) & 1u);
    return (u16)(u >> 16);
}

__device__ __forceinline__ float fexp2(float x) {
#if __has_builtin(__builtin_amdgcn_exp2f)
    return __builtin_amdgcn_exp2f(x);
#else
    return exp2f(x);
#endif
}

// pack two rounded f32 -> bf16 pair in one dword (a low16, b high16) — proven path
__device__ __forceinline__ unsigned pack_bf16(float a, float b) {
    unsigned ua = __float_as_uint(a) + 0x8000u;
    unsigned ub = __float_as_uint(b) + 0x8000u;
    return __builtin_amdgcn_perm(ub, ua, 0x07060302u);
}

#if __has_builtin(__builtin_amdgcn_mfma_f32_16x16x16bf16_1k)
__device__ __forceinline__ f32x4 mfma16(short4v a, short4v b, f32x4 c) {
    return __builtin_amdgcn_mfma_f32_16x16x16bf16_1k(a, b, c, 0, 0, 0);
}
#else
__device__ __forceinline__ f32x4 mfma16(short4v a, short4v b, f32x4 c) {
    short8 a8 = {a[0], a[1], a[2], a[3], 0, 0, 0, 0};
    short8 b8 = {b[0], b[1], b[2], b[3], 0, 0, 0, 0};
    return __builtin_amdgcn_mfma_f32_16x16x32_bf16(a8, b8, c, 0, 0, 0);
}
#endif

__device__ __forceinline__ void gload_lds16(const u16* g, u16* l) {
    __builtin_amdgcn_global_load_lds(
        (const __attribute__((address_space(1))) void*)(g),
        (__attribute__((address_space(3))) void*)(l),
        16, 0, 0);
}

// ---------------- fused prep: Wo transpose | cast x | Wq/Wk/Wv transposes ------
// grid = (16, 16, 5): z=0 Wo (x,y tile); z=1 cast x (flat 256 blocks);
// z=2..4 W{q,k,v}: y = head, x = 64-row tile of d.
__global__ __launch_bounds__(256) void prep_kernel(
    const float* __restrict__ x,
    const float* __restrict__ Wq, const float* __restrict__ Wk,
    const float* __restrict__ Wv, const float* __restrict__ Wo,
    u16* __restrict__ xb, u16* __restrict__ wqkv, u16* __restrict__ wot)
{
    __shared__ u16 tile[64][65];
    const int z = blockIdx.z;
    const int tc = threadIdx.x & 63, tr = threadIdx.x >> 6;

    if (z == 1) {
        // cast x: 4,194,304 f32 -> bf16; 256 blocks x 256 thr x 16 float4
        const int blk = blockIdx.y * 16 + blockIdx.x;
        const int base = (blk * 256 + threadIdx.x) * 4;
        #pragma unroll
        for (int i = 0; i < 16; ++i) {
            const int idx = base + i * 262144;
            float4 v = *(const float4*)(x + idx);
            u16x4 o;
            o.x = f2bf(v.x); o.y = f2bf(v.y); o.z = f2bf(v.z); o.w = f2bf(v.w);
            *(u16x4*)(xb + idx) = o;
        }
        return;
    }

    const float* src;
    u16* dst;
    int C, R, rb, cb;
    if (z == 0) {
        src = Wo; dst = wot; C = 1024; R = 1024;
        rb = blockIdx.x * 64; cb = blockIdx.y * 64;
    } else {
        const float* W = (z == 2) ? Wq : (z == 3) ? Wk : Wv;
        const int head = blockIdx.y;
        src = W + head * 65536;                                  // [1024][64]
        dst = wqkv + (size_t)(z - 2) * 1048576 + head * 65536;   // rows e, cols d
        C = 64; R = 1024;
        rb = blockIdx.x * 64; cb = 0;
    }
    #pragma unroll
    for (int i = 0; i < 64; i += 4)
        tile[tr + i][tc] = f2bf(src[(size_t)(rb + tr + i) * C + (cb + tc)]);
    __syncthreads();
    #pragma unroll
    for (int i = 0; i < 64; i += 4)
        dst[(size_t)(cb + tr + i) * R + (rb + tc)] = tile[tc][tr + i];
}

// ---------------- QKV GEMM: [4096,1024] x [3072,1024]^T ----------------
// grid (24 n-tiles, 32 m-tiles): consecutive dispatches share the X tile -> L2 reuse.
// __launch_bounds__(256,3): cap unified VGPR+AGPR so 3 blocks/CU are resident.
// Epilogue: +bias; Q*0.125*log2e -> q[bh][s][64]; K -> k[bh][t][64];
//           V -> V2[bh][s/16][e=64][s%16]  (16-key-tiled transpose)
__global__ __launch_bounds__(256, 3) void gemm_qkv_kernel(
    const u16* __restrict__ X, const u16* __restrict__ W,
    const float* __restrict__ bq, const float* __restrict__ bk,
    const float* __restrict__ bv,
    u16* __restrict__ qo, u16* __restrict__ ko, u16* __restrict__ vto)
{
    __shared__ __align__(16) u16 As[128 * 32];
    __shared__ __align__(16) u16 Bs[128 * 32];
    const int tid = threadIdx.x;
    const int lane = tid & 63;
    const int wv = tid >> 6;
    const int wm = wv & 1, wn = wv >> 1;
    const int m0 = blockIdx.y * 128;
    const int n0 = blockIdx.x * 128;
    const int c = lane & 15, qd = lane >> 4;

    f32x4 acc[4][4];
    #pragma unroll
    for (int a = 0; a < 4; ++a)
        #pragma unroll
        for (int b2 = 0; b2 < 4; ++b2) acc[a][b2] = f32x4{0.f, 0.f, 0.f, 0.f};

    const u16* Xb = X + (size_t)m0 * 1024;
    const u16* Wb = W + (size_t)n0 * 1024;

    for (int kt = 0; kt < 1024; kt += 32) {
        #pragma unroll
        for (int i = 0; i < 2; ++i) {
            int slot = i * 256 + tid;
            int row = slot >> 2, part = slot & 3;
            gload_lds16(Xb + (size_t)row * 1024 + kt + part * 8, &As[slot * 8]);
            gload_lds16(Wb + (size_t)row * 1024 + kt + part * 8, &Bs[slot * 8]);
        }
        __syncthreads();
        short8 af[4], bf[4];
        #pragma unroll
        for (int mt = 0; mt < 4; ++mt)
            af[mt] = *(const short8*)&As[(wm * 64 + mt * 16 + c) * 32 + qd * 8];
        #pragma unroll
        for (int nt = 0; nt < 4; ++nt)
            bf[nt] = *(const short8*)&Bs[(wn * 64 + nt * 16 + c) * 32 + qd * 8];
        #pragma unroll
        for (int mt = 0; mt < 4; ++mt)
            #pragma unroll
            for (int nt = 0; nt < 4; ++nt)
                acc[mt][nt] = __builtin_amdgcn_mfma_f32_16x16x32_bf16(af[mt], bf[nt], acc[mt][nt], 0, 0, 0);
        __syncthreads();
    }

    // epilogue: n -> (mat, h, e); m -> (b, s)
    #pragma unroll
    for (int mt = 0; mt < 4; ++mt) {
        const int mbase = m0 + wm * 64 + mt * 16 + qd * 4;
        const int b = mbase >> 11;
        #pragma unroll
        for (int nt = 0; nt < 4; ++nt) {
            const int n = n0 + wn * 64 + nt * 16 + c;
            const int mat = n >> 10;
            const int idx = n & 1023;
            const int h = idx >> 6, e = idx & 63;
            const float bias = (mat == 0 ? bq : (mat == 1 ? bk : bv))[idx];
            if (mat == 2) {
                const int s = mbase & 2047;
                u16x4 pv;
                pv.x = f2bf(acc[mt][nt][0] + bias);
                pv.y = f2bf(acc[mt][nt][1] + bias);
                pv.z = f2bf(acc[mt][nt][2] + bias);
                pv.w = f2bf(acc[mt][nt][3] + bias);
                *(u16x4*)(vto + ((((size_t)(b * 16 + h) * 128 + (s >> 4)) * 64 + e) * 16
                                 + (s & 15))) = pv;
            } else {
                const float scale = (mat == 0) ? 0.18033688011112042f : 1.0f;
                u16* dst = (mat == 0) ? qo : ko;
                #pragma unroll
                for (int r = 0; r < 4; ++r) {
                    const int s = (mbase + r) & 2047;
                    dst[((size_t)((b * 16 + h) * 2048 + s)) * 64 + e] =
                        f2bf((acc[mt][nt][r] + bias) * scale);
                }
            }
        }
    }
}

// ---------------- flash attention v10: v8 body + XCD-LOCAL work stealing -------
// R3 post-mortem: global stealing fixed the tail but destroyed bh->XCD locality
// (FETCH 12.3MB -> 72-78MB, flash 53.4 -> 76us): K/V went from L2-hit (~200cy)
// to HBM-miss (~900cy), which the 2-deep prefetch can't hide. R2 showed flash is
// latency/tail-bound, not issue-bound. v10 keeps BOTH properties:
//  * 8 per-XCD counters (64B apart). Block group = bid&7 (dispatch round-robin
//    -> same XCD heuristic v8's pinning relied on; pure locality heuristic,
//    never a correctness dependence — any block may run any of its group's
//    tiles, each tile runs exactly once).
//  * group g owns tiles tt in [0,128): bh = g*4 + (tt>>5), q0 = (tt&31)*64 —
//    identical tile->XCD map as v8, so K+V stay L2-resident per XCD.
//  * K-loop body byte-identical to passing v8; multi-tile pool-reuse loop
//    structure proven correct in R3.
// tcnt == nullptr -> static fallback reproducing v8's exact mapping.
__global__ __launch_bounds__(256, 3) void flash_kernel(
    const u16* __restrict__ Q,   // [32][2048][64], pre-scaled by 0.125*log2e
    const u16* __restrict__ K,   // [32][2048][64]
    const u16* __restrict__ V2,  // [32][128][64][16]
    u16* __restrict__ ctx,       // [4096][1024] = [b*2048+s][h*64+e]
    unsigned* tcnt)              // 8 steal counters (ws+48MiB, 64B stride) or nullptr
{
    __shared__ __align__(16) char pool[34816];
    __shared__ unsigned sh_t;
    u16* stage = (u16*)pool;                              // K ring-3: 4w*3072 u16 = 24576 B
    float (*Os)[64][66] = (float (*)[64][66])pool;        // merge (aliased): 33792 B
    float (*Ls)[64] = (float (*)[64])(pool + 33792);      // 1 KB (no stage alias)

    const int tid = threadIdx.x, lane = tid & 63, w = tid >> 6;
    const int c = lane & 15, qd = lane >> 4;
    const int bid = blockIdx.x;
    const int grp = bid & 7;                 // XCD group (round-robin heuristic)
    unsigned* ctr = tcnt ? tcnt + grp * 16 : nullptr;
    // static fallback tile id == v8's mapping: bh=(bid&7)*4+((bid>>3)&3), q0=(bid>>5)*64
    const unsigned t_static = (unsigned)((((bid >> 3) & 3) << 5) | (bid >> 5));

    u16* Kst = stage + w * 3072;             // 3 K slots x 1024 u16

    const int krow8 = lane >> 3;                    // row within 8-row group
    const int kgc = (lane & 7) ^ (krow8 & 7);       // pre-swizzled source chunk
    const int voff = c * 16 + qd * 4;               // per-lane V fragment offset

    for (;;) {
        if (tid == 0)
            sh_t = ctr ? atomicAdd(ctr, 1u) : t_static;
        __syncthreads();                       // broadcast t; pool-reuse fence
        const unsigned t = sh_t;
        if (t >= 128u) break;

        const int bh = grp * 4 + (int)(t >> 5);  // this group's 4 bh only
        const int q0 = (int)(t & 31) << 6;       // 0..1984
        const int b = bh >> 4, h = bh & 15;
        const u16* Qh = Q + (size_t)bh * 131072;
        const u16* Kh = K + (size_t)bh * 131072;
        const u16* Vh = V2 + (size_t)bh * 131072;

        short8 qf[4][2];
        #pragma unroll
        for (int qb = 0; qb < 4; ++qb)
            #pragma unroll
            for (int kb = 0; kb < 2; ++kb)
                qf[qb][kb] = *(const short8*)&Qh[(size_t)(q0 + qb * 16 + c) * 64 + kb * 32 + qd * 8];

        f32x4 o[4][4];        // o[mt][qb]: e = mt*16 + qd*4 + r, q = qb*16 + c
        float lsum[4];        // per-lane P row-sum partial (keys qd*4+r per tile)
        #pragma unroll
        for (int mt = 0; mt < 4; ++mt)
            #pragma unroll
            for (int qb = 0; qb < 4; ++qb) o[mt][qb] = f32x4{0.f, 0.f, 0.f, 0.f};
        #pragma unroll
        for (int qb = 0; qb < 4; ++qb) lsum[qb] = 0.f;

        // prologue: K0 -> slot0; V0 -> vA regs; K1 -> slot1
        #pragma unroll
        for (int j = 0; j < 2; ++j) {
            const int row = j * 8 + krow8;
            gload_lds16(Kh + (size_t)(w * 512 + row) * 64 + kgc * 8,
                        Kst + j * 512 + lane * 8);
        }
        short4v vA[4], vB[4];
        {
            const u16* vb = Vh + (size_t)(w * 32) * 1024 + voff;
            #pragma unroll
            for (int mt = 0; mt < 4; ++mt)
                vA[mt] = *(const short4v*)(vb + mt * 256);
        }
        #pragma unroll
        for (int j = 0; j < 2; ++j) {
            const int row = j * 8 + krow8;
            gload_lds16(Kh + (size_t)(w * 512 + 16 + row) * 64 + kgc * 8,
                        Kst + 1024 + j * 512 + lane * 8);
        }

        int cur = 0;
        auto body = [&](int it, short4v (&VC)[4], short4v (&VN)[4]) {
            u16* Kb = Kst + cur * 1024;

            __builtin_amdgcn_s_waitcnt(0xF74);   // vmcnt(4): K(it) staged
            __builtin_amdgcn_sched_barrier(0);

            short8 kf[2];
            #pragma unroll
            for (int kb = 0; kb < 2; ++kb)
                kf[kb] = *(const short8*)&Kb[c * 64 + ((4 * kb + qd) ^ (c & 7)) * 8];

            __builtin_amdgcn_sched_barrier(0);

            // V register prefetch for it+1 (wrap &31: harmless dummy re-read)
            {
                const int itn = (it + 1) & 31;
                const u16* vb = Vh + (size_t)(w * 32 + itn) * 1024 + voff;
                #pragma unroll
                for (int mt = 0; mt < 4; ++mt)
                    VN[mt] = *(const short4v*)(vb + mt * 256);
            }
            // K stage for it+2 into (cur+2)%3
            {
                const int itn = (it + 2) & 31;
                const int t0n = w * 512 + itn * 16;
                const int nslot = (cur >= 1) ? cur - 1 : 2;
                u16* Kn = Kst + nslot * 1024;
                #pragma unroll
                for (int j = 0; j < 2; ++j) {
                    const int row = j * 8 + krow8;
                    gload_lds16(Kh + (size_t)(t0n + row) * 64 + kgc * 8,
                                Kn + j * 512 + lane * 8);
                }
            }

            f32x4 sc[4];
            #pragma unroll
            for (int qb = 0; qb < 4; ++qb) {
                sc[qb] = f32x4{0.f, 0.f, 0.f, 0.f};
                sc[qb] = __builtin_amdgcn_mfma_f32_16x16x32_bf16(kf[0], qf[qb][0], sc[qb], 0, 0, 0);
                sc[qb] = __builtin_amdgcn_mfma_f32_16x16x32_bf16(kf[1], qf[qb][1], sc[qb], 0, 0, 0);
            }

            short4v pb[4];
            #pragma unroll
            for (int qb = 0; qb < 4; ++qb) {
                float p0 = fexp2(sc[qb][0]);
                float p1 = fexp2(sc[qb][1]);
                float p2 = fexp2(sc[qb][2]);
                float p3 = fexp2(sc[qb][3]);
                lsum[qb] += (p0 + p1) + (p2 + p3);
                unsigned d0 = pack_bf16(p0, p1);
                unsigned d1 = pack_bf16(p2, p3);
                union { unsigned u[2]; short4v s; } pu;
                pu.u[0] = d0; pu.u[1] = d1;
                pb[qb] = pu.s;
            }

            #pragma unroll
            for (int qb = 0; qb < 4; ++qb)
                #pragma unroll
                for (int mt = 0; mt < 4; ++mt)
                    o[mt][qb] = mfma16(VC[mt], pb[qb], o[mt][qb]);

            cur = (cur == 2) ? 0 : cur + 1;
        };

        for (int it2 = 0; it2 < 16; ++it2) {
            body(2 * it2, vA, vB);
            body(2 * it2 + 1, vB, vA);
        }

        __builtin_amdgcn_s_waitcnt(0xF70);   // vmcnt(0) before aliasing the pool
        __syncthreads();

        // finish l: fold the 4 qd-groups into a full 512-key wave sum
        #pragma unroll
        for (int qb = 0; qb < 4; ++qb) {
            lsum[qb] += __shfl_xor(lsum[qb], 16, 64);
            lsum[qb] += __shfl_xor(lsum[qb], 32, 64);
        }
        if (qd == 0) {
            #pragma unroll
            for (int qb = 0; qb < 4; ++qb) Ls[w][qb * 16 + c] = lsum[qb];
        }

        if (w >= 2) {
            float (*S)[66] = Os[w - 2];
            #pragma unroll
            for (int mt = 0; mt < 4; ++mt)
                #pragma unroll
                for (int qb = 0; qb < 4; ++qb)
                    #pragma unroll
                    for (int r = 0; r < 4; ++r)
                        S[mt * 16 + qd * 4 + r][qb * 16 + c] = o[mt][qb][r];
        }
        __syncthreads();
        if (w < 2) {
            float (*S)[66] = Os[w];
            #pragma unroll
            for (int mt = 0; mt < 4; ++mt)
                #pragma unroll
                for (int qb = 0; qb < 4; ++qb)
                    #pragma unroll
                    for (int r = 0; r < 4; ++r)
                        o[mt][qb][r] += S[mt * 16 + qd * 4 + r][qb * 16 + c];
        }
        __syncthreads();
        if (w == 1) {
            float (*S)[66] = Os[0];
            #pragma unroll
            for (int mt = 0; mt < 4; ++mt)
                #pragma unroll
                for (int qb = 0; qb < 4; ++qb)
                    #pragma unroll
                    for (int r = 0; r < 4; ++r)
                        S[mt * 16 + qd * 4 + r][qb * 16 + c] = o[mt][qb][r];
        }
        __syncthreads();
        if (w == 0) {
            float (*S)[66] = Os[0];
            float inv[4];
            #pragma unroll
            for (int qb = 0; qb < 4; ++qb) {
                int q = qb * 16 + c;
                float l = (Ls[0][q] + Ls[1][q]) + (Ls[2][q] + Ls[3][q]);
                inv[qb] = __builtin_amdgcn_rcpf(l);
            }
            #pragma unroll
            for (int mt = 0; mt < 4; ++mt)
                #pragma unroll
                for (int qb = 0; qb < 4; ++qb) {
                    u16x4 ov;
                    #pragma unroll
                    for (int r = 0; r < 4; ++r) {
                        float v = (o[mt][qb][r] + S[mt * 16 + qd * 4 + r][qb * 16 + c]) * inv[qb];
                        ((u16*)&ov)[r] = f2bf(v);
                    }
                    *(u16x4*)&ctx[((size_t)(b * 2048 + q0 + qb * 16 + c)) * 1024
                                  + h * 64 + mt * 16 + qd * 4] = ov;
                }
        }

        __syncthreads();   // all waves consumed sh_t before tid0 re-writes it
        if (!ctr) break;   // static fallback: one tile per block
    }
}

// ---------------- output projection: ctx[4096,1024] x Wo^T + bo, 64x128 tiles ----
__global__ __launch_bounds__(256, 4) void gemm_out_kernel(
    const u16* __restrict__ A, const u16* __restrict__ Wt,
    const float* __restrict__ bo, float* __restrict__ out)
{
    __shared__ __align__(16) u16 As[64 * 32];
    __shared__ __align__(16) u16 Bs[128 * 32];
    const int tid = threadIdx.x;
    const int lane = tid & 63;
    const int wv = tid >> 6;
    const int wm = wv & 1, wn = wv >> 1;
    const int m0 = blockIdx.x * 64;
    const int n0 = blockIdx.y * 128;
    const int c = lane & 15, qd = lane >> 4;

    f32x4 acc[2][4];
    #pragma unroll
    for (int a = 0; a < 2; ++a)
        #pragma unroll
        for (int b2 = 0; b2 < 4; ++b2) acc[a][b2] = f32x4{0.f, 0.f, 0.f, 0.f};

    const u16* Ab = A + (size_t)m0 * 1024;
    const u16* Wb = Wt + (size_t)n0 * 1024;

    for (int kt = 0; kt < 1024; kt += 32) {
        {
            int row = tid >> 2, part = tid & 3;
            gload_lds16(Ab + (size_t)row * 1024 + kt + part * 8, &As[tid * 8]);
        }
        #pragma unroll
        for (int i = 0; i < 2; ++i) {
            int slot = i * 256 + tid;
            int row = slot >> 2, part = slot & 3;
            gload_lds16(Wb + (size_t)row * 1024 + kt + part * 8, &Bs[slot * 8]);
        }
        __syncthreads();
        short8 af[2], bf[4];
        #pragma unroll
        for (int mt = 0; mt < 2; ++mt)
            af[mt] = *(const short8*)&As[(wm * 32 + mt * 16 + c) * 32 + qd * 8];
        #pragma unroll
        for (int nt = 0; nt < 4; ++nt)
            bf[nt] = *(const short8*)&Bs[(wn * 64 + nt * 16 + c) * 32 + qd * 8];
        #pragma unroll
        for (int mt = 0; mt < 2; ++mt)
            #pragma unroll
            for (int nt = 0; nt < 4; ++nt)
                acc[mt][nt] = __builtin_amdgcn_mfma_f32_16x16x32_bf16(af[mt], bf[nt], acc[mt][nt], 0, 0, 0);
        __syncthreads();
    }

    #pragma unroll
    for (int mt = 0; mt < 2; ++mt) {
        const int mbase = m0 + wm * 32 + mt * 16 + qd * 4;
        #pragma unroll
        for (int nt = 0; nt < 4; ++nt) {
            const int n = n0 + wn * 64 + nt * 16 + c;
            const float bias = bo[n];
            #pragma unroll
            for (int r = 0; r < 4; ++r)
                out[(size_t)(mbase + r) * 1024 + n] = acc[mt][nt][r] + bias;
        }
    }
}

extern "C" void kernel_launch(void* const* d_in, const int* in_sizes, int n_in,
                              void* d_out, int out_size, void* d_ws, size_t ws_size,
                              hipStream_t stream) {
    const float* x  = (const float*)d_in[0];
    const float* Wq = (const float*)d_in[1];
    const float* bq = (const float*)d_in[2];
    const float* Wk = (const float*)d_in[3];
    const float* bk = (const float*)d_in[4];
    const float* Wv = (const float*)d_in[5];
    const float* bv = (const float*)d_in[6];
    const float* Wo = (const float*)d_in[7];
    const float* bo = (const float*)d_in[8];
    float* out = (float*)d_out;

    u16* ws    = (u16*)d_ws;
    u16* xb    = ws;                          // 4096*1024
    u16* wqkv  = xb + 4096 * 1024;            // 3072*1024
    u16* wot   = wqkv + 3072 * 1024;          // 1024*1024
    u16* qws   = wot + 1024 * 1024;           // 32*2048*64
    u16* kws   = qws + 4194304;               // 32*2048*64
    u16* v2ws  = kws + 4194304;               // 32*128*64*16
    u16* ctxws = v2ws + 4194304;              // 4096*1024
    // buffers end at byte 50,331,648 (48 MiB); 8 steal counters (64B apart) after.
    const size_t cnt_off = 50331648;
    unsigned* tcnt = (ws_size >= cnt_off + 1024)
                   ? (unsigned*)((char*)d_ws + cnt_off) : nullptr;

    prep_kernel<<<dim3(16, 16, 5), 256, 0, stream>>>(x, Wq, Wk, Wv, Wo, xb, wqkv, wot);
    gemm_qkv_kernel<<<dim3(24, 32), 256, 0, stream>>>(xb, wqkv, bq, bk, bv, qws, kws, v2ws);
    if (tcnt) hipMemsetAsync(tcnt, 0, 512, stream);
    flash_kernel<<<1024, 256, 0, stream>>>(qws, kws, v2ws, ctxws, tcnt);
    gemm_out_kernel<<<dim3(64, 8), 256, 0, stream>>>(ctxws, wot, bo, out);
}

// Round 5
// 194.959 us; speedup vs baseline: 1.1019x; 1.0271x over previous
//
#include <hip/hip_runtime.h>
#include <cstdint>

typedef unsigned short u16;
typedef __attribute__((ext_vector_type(8))) short short8;
typedef __attribute__((ext_vector_type(4))) short short4v;
typedef __attribute__((ext_vector_type(4))) float f32x4;
typedef __attribute__((ext_vector_type(4))) unsigned short u16x4;

__device__ __forceinline__ u16 f2bf(float x) {
    unsigned int u = __float_as_uint(x);
    u += 0x7fffu + ((u >> 16) & 1u);
    return (u16)(u >> 16);
}

__device__ __forceinline__ float fexp2(float x) {
#if __has_builtin(__builtin_amdgcn_exp2f)
    return __builtin_amdgcn_exp2f(x);
#else
    return exp2f(x);
#endif
}

// pack two rounded f32 -> bf16 pair in one dword (a low16, b high16) — proven path
__device__ __forceinline__ unsigned pack_bf16(float a, float b) {
    unsigned ua = __float_as_uint(a) + 0x8000u;
    unsigned ub = __float_as_uint(b) + 0x8000u;
    return __builtin_amdgcn_perm(ub, ua, 0x07060302u);
}

#if __has_builtin(__builtin_amdgcn_mfma_f32_16x16x16bf16_1k)
__device__ __forceinline__ f32x4 mfma16(short4v a, short4v b, f32x4 c) {
    return __builtin_amdgcn_mfma_f32_16x16x16bf16_1k(a, b, c, 0, 0, 0);
}
#else
__device__ __forceinline__ f32x4 mfma16(short4v a, short4v b, f32x4 c) {
    short8 a8 = {a[0], a[1], a[2], a[3], 0, 0, 0, 0};
    short8 b8 = {b[0], b[1], b[2], b[3], 0, 0, 0, 0};
    return __builtin_amdgcn_mfma_f32_16x16x32_bf16(a8, b8, c, 0, 0, 0);
}
#endif

__device__ __forceinline__ void gload_lds16(const u16* g, u16* l) {
    __builtin_amdgcn_global_load_lds(
        (const __attribute__((address_space(1))) void*)(g),
        (__attribute__((address_space(3))) void*)(l),
        16, 0, 0);
}

// ---------------- fused prep: Wo transpose | cast x | Wq/Wk/Wv transposes ------
__global__ __launch_bounds__(256) void prep_kernel(
    const float* __restrict__ x,
    const float* __restrict__ Wq, const float* __restrict__ Wk,
    const float* __restrict__ Wv, const float* __restrict__ Wo,
    u16* __restrict__ xb, u16* __restrict__ wqkv, u16* __restrict__ wot)
{
    __shared__ u16 tile[64][65];
    const int z = blockIdx.z;
    const int tc = threadIdx.x & 63, tr = threadIdx.x >> 6;

    if (z == 1) {
        const int blk = blockIdx.y * 16 + blockIdx.x;
        const int base = (blk * 256 + threadIdx.x) * 4;
        #pragma unroll
        for (int i = 0; i < 16; ++i) {
            const int idx = base + i * 262144;
            float4 v = *(const float4*)(x + idx);
            u16x4 o;
            o.x = f2bf(v.x); o.y = f2bf(v.y); o.z = f2bf(v.z); o.w = f2bf(v.w);
            *(u16x4*)(xb + idx) = o;
        }
        return;
    }

    const float* src;
    u16* dst;
    int C, R, rb, cb;
    if (z == 0) {
        src = Wo; dst = wot; C = 1024; R = 1024;
        rb = blockIdx.x * 64; cb = blockIdx.y * 64;
    } else {
        const float* W = (z == 2) ? Wq : (z == 3) ? Wk : Wv;
        const int head = blockIdx.y;
        src = W + head * 65536;                                  // [1024][64]
        dst = wqkv + (size_t)(z - 2) * 1048576 + head * 65536;   // rows e, cols d
        C = 64; R = 1024;
        rb = blockIdx.x * 64; cb = 0;
    }
    #pragma unroll
    for (int i = 0; i < 64; i += 4)
        tile[tr + i][tc] = f2bf(src[(size_t)(rb + tr + i) * C + (cb + tc)]);
    __syncthreads();
    #pragma unroll
    for (int i = 0; i < 64; i += 4)
        dst[(size_t)(cb + tr + i) * R + (rb + tc)] = tile[tc][tr + i];
}

// ---------------- QKV GEMM v2: 256x256 tile, BK=32, counted-vmcnt pipeline ----
// C[4096,3072] = X[4096,1024] . W[3072,1024]^T.  Grid: 192 blocks (16m x 12n),
// single tranche; 512 thr = 8 waves (2m x 4n); per-wave 128x64 out = acc[8][4].
// LDS 64 KiB: 2 buffers x (A[256][32] + B[256][32]) bf16, XOR chunk-swizzled.
//   stage:  LDS slot (row, cs) <- global chunk cg = cs ^ ((row>>1)&3)
//           (per-lane: cg = (lane&3) ^ ((lane>>3)&3) — flash-K-ring pattern)
//   read:   chunk for k-quad qd at cs = qd ^ ((c>>1)&3) — lane-constant;
//           lanes c=0..15 then span 8 distinct 4-bank groups -> 2-way (free).
// Pipeline (T3/T4 core): stage of tile t+2 issued at END of iter t (its buffer's
// reads just completed), so at the gate of iter t the queue is [T_t(4) oldest,
// T_{t+1}(4)] -> s_waitcnt vmcnt(4) waits only the oldest 4; NEVER drains in the
// loop (last iter peeled with vmcnt(0)). Raw s_barrier (not __syncthreads — that
// would emit the vmcnt(0) drain); sched_barrier(0) fences pin vmem/ds motion.
// Epilogue: verbatim proven mapping (+bias, Q scale, V2 16-key transpose).
__global__ __launch_bounds__(512, 2) void gemm_qkv_kernel(
    const u16* __restrict__ X, const u16* __restrict__ W,
    const float* __restrict__ bq, const float* __restrict__ bk,
    const float* __restrict__ bv,
    u16* __restrict__ qo, u16* __restrict__ ko, u16* __restrict__ vto)
{
    __shared__ __align__(16) u16 lds[32768];   // 64 KiB: [p][A 8192 | B 8192]
    const int tid = threadIdx.x;
    const int lane = tid & 63;
    const int wid = tid >> 6;            // 0..7
    const int wm = wid >> 2;             // 0..1  (128-row half)
    const int wn = wid & 3;              // 0..3  (64-col quarter)
    const int c = lane & 15, qd = lane >> 4;

    // XCD swizzle: 192 = 8 XCD x 24; within XCD 2 m-panels x 12 n-panels.
    const int id = (blockIdx.x & 7) * 24 + (blockIdx.x >> 3);
    const int m0 = (id / 12) * 256;
    const int n0 = (id % 12) * 256;

    const u16* Xb = X + (size_t)m0 * 1024;
    const u16* Wb = W + (size_t)n0 * 1024;

    // per-lane staging constants
    const int srow = tid >> 2;                       // 0..127 (+ j*128)
    const int scg  = (lane & 3) ^ ((lane >> 3) & 3); // pre-swizzled global chunk
    // per-lane read constant: swizzled chunk offset (u16) for this lane's k-quad
    const int cof = (qd ^ ((c >> 1) & 3)) * 8;
    const int rA0 = wm * 128 + c;
    const int rB0 = wn * 64 + c;

    auto stage = [&](int t, int p) {
        const int pb = p * 16384;
        #pragma unroll
        for (int j = 0; j < 2; ++j) {
            const int row = j * 128 + srow;
            const u16* gs = Xb + (size_t)row * 1024 + t * 32 + scg * 8;
            gload_lds16(gs, &lds[pb + (j * 512 + tid) * 8]);
            const u16* gw = Wb + (size_t)row * 1024 + t * 32 + scg * 8;
            gload_lds16(gw, &lds[pb + 8192 + (j * 512 + tid) * 8]);
        }
    };

    f32x4 acc[8][4];
    #pragma unroll
    for (int mi = 0; mi < 8; ++mi)
        #pragma unroll
        for (int ni = 0; ni < 4; ++ni) acc[mi][ni] = f32x4{0.f, 0.f, 0.f, 0.f};

    auto body = [&](int t) {
        const int pb = (t & 1) * 16384;
        __builtin_amdgcn_sched_barrier(0);
        __builtin_amdgcn_s_barrier();
        __builtin_amdgcn_sched_barrier(0);
        short8 af[8], bf[4];
        #pragma unroll
        for (int mi = 0; mi < 8; ++mi)
            af[mi] = *(const short8*)&lds[pb + (rA0 + mi * 16) * 32 + cof];
        #pragma unroll
        for (int ni = 0; ni < 4; ++ni)
            bf[ni] = *(const short8*)&lds[pb + 8192 + (rB0 + ni * 16) * 32 + cof];
        __builtin_amdgcn_s_setprio(1);
        #pragma unroll
        for (int mi = 0; mi < 8; ++mi)
            #pragma unroll
            for (int ni = 0; ni < 4; ++ni)
                acc[mi][ni] = __builtin_amdgcn_mfma_f32_16x16x32_bf16(af[mi], bf[ni], acc[mi][ni], 0, 0, 0);
        __builtin_amdgcn_s_setprio(0);
        __builtin_amdgcn_sched_barrier(0);
        __builtin_amdgcn_s_barrier();   // all reads of this buffer done
    };

    // prologue: T0 -> P0, T1 -> P1  (4 loads each)
    stage(0, 0);
    stage(1, 1);
    __builtin_amdgcn_sched_barrier(0);

    for (int t = 0; t < 31; ++t) {
        __builtin_amdgcn_s_waitcnt(0xF74);   // vmcnt(4): T_t landed, T_{t+1} flying
        body(t);
        if (t < 30) stage(t + 2, t & 1);     // into the buffer just released
        __builtin_amdgcn_sched_barrier(0);
    }
    __builtin_amdgcn_s_waitcnt(0xF70);       // final tile: drain
    body(31);

    // epilogue: n -> (mat, h, e); m -> (b, s)   [proven mapping]
    #pragma unroll
    for (int mi = 0; mi < 8; ++mi) {
        const int mbase = m0 + wm * 128 + mi * 16 + qd * 4;
        const int b = mbase >> 11;
        #pragma unroll
        for (int ni = 0; ni < 4; ++ni) {
            const int n = n0 + wn * 64 + ni * 16 + c;
            const int mat = n >> 10;
            const int idx = n & 1023;
            const int h = idx >> 6, e = idx & 63;
            const float bias = (mat == 0 ? bq : (mat == 1 ? bk : bv))[idx];
            if (mat == 2) {
                const int s = mbase & 2047;
                u16x4 pv;
                pv.x = f2bf(acc[mi][ni][0] + bias);
                pv.y = f2bf(acc[mi][ni][1] + bias);
                pv.z = f2bf(acc[mi][ni][2] + bias);
                pv.w = f2bf(acc[mi][ni][3] + bias);
                *(u16x4*)(vto + ((((size_t)(b * 16 + h) * 128 + (s >> 4)) * 64 + e) * 16
                                 + (s & 15))) = pv;
            } else {
                const float scale = (mat == 0) ? 0.18033688011112042f : 1.0f;
                u16* dst = (mat == 0) ? qo : ko;
                #pragma unroll
                for (int r = 0; r < 4; ++r) {
                    const int s = (mbase + r) & 2047;
                    dst[((size_t)((b * 16 + h) * 2048 + s)) * 64 + e] =
                        f2bf((acc[mi][ni][r] + bias) * scale);
                }
            }
        }
    }
}

// ---------------- flash attention v8 (restored verbatim — proven 53.4 us) ------
__global__ __launch_bounds__(256, 3) void flash_kernel(
    const u16* __restrict__ Q,   // [32][2048][64], pre-scaled by 0.125*log2e
    const u16* __restrict__ K,   // [32][2048][64]
    const u16* __restrict__ V2,  // [32][128][64][16]
    u16* __restrict__ ctx)       // [4096][1024] = [b*2048+s][h*64+e]
{
    __shared__ __align__(16) char pool[34816];
    u16* stage = (u16*)pool;                              // K ring-3: 4w*3072 u16
    float (*Os)[64][66] = (float (*)[64][66])pool;        // merge (aliased)
    float (*Ls)[64] = (float (*)[64])(pool + 33792);      // 1 KB

    const int tid = threadIdx.x, lane = tid & 63, w = tid >> 6;
    const int c = lane & 15, qd = lane >> 4;
    const int bid = blockIdx.x;
    const int r5 = bid & 31;
    const int bh = (r5 & 7) * 4 + (r5 >> 3);   // pin each bh's blocks to one XCD
    const int q0 = (bid >> 5) * 64;
    const int b = bh >> 4, h = bh & 15;
    const u16* Qh = Q + (size_t)bh * 2048 * 64;
    const u16* Kh = K + (size_t)bh * 2048 * 64;
    const u16* Vh = V2 + (size_t)bh * 128 * 1024;

    u16* Kst = stage + w * 3072;             // 3 K slots x 1024 u16

    const int krow8 = lane >> 3;
    const int kgc = (lane & 7) ^ (krow8 & 7);
    const int voff = c * 16 + qd * 4;

    short8 qf[4][2];
    #pragma unroll
    for (int qb = 0; qb < 4; ++qb)
        #pragma unroll
        for (int kb = 0; kb < 2; ++kb)
            qf[qb][kb] = *(const short8*)&Qh[(size_t)(q0 + qb * 16 + c) * 64 + kb * 32 + qd * 8];

    f32x4 o[4][4];
    float lsum[4];
    #pragma unroll
    for (int mt = 0; mt < 4; ++mt)
        #pragma unroll
        for (int qb = 0; qb < 4; ++qb) o[mt][qb] = f32x4{0.f, 0.f, 0.f, 0.f};
    #pragma unroll
    for (int qb = 0; qb < 4; ++qb) lsum[qb] = 0.f;

    #pragma unroll
    for (int j = 0; j < 2; ++j) {
        const int row = j * 8 + krow8;
        gload_lds16(Kh + (size_t)(w * 512 + row) * 64 + kgc * 8,
                    Kst + j * 512 + lane * 8);
    }
    short4v vA[4], vB[4];
    {
        const u16* vb = Vh + (size_t)(w * 32) * 1024 + voff;
        #pragma unroll
        for (int mt = 0; mt < 4; ++mt)
            vA[mt] = *(const short4v*)(vb + mt * 256);
    }
    #pragma unroll
    for (int j = 0; j < 2; ++j) {
        const int row = j * 8 + krow8;
        gload_lds16(Kh + (size_t)(w * 512 + 16 + row) * 64 + kgc * 8,
                    Kst + 1024 + j * 512 + lane * 8);
    }

    int cur = 0;
    auto body = [&](int it, short4v (&VC)[4], short4v (&VN)[4]) {
        u16* Kb = Kst + cur * 1024;

        __builtin_amdgcn_s_waitcnt(0xF74);   // vmcnt(4): K(it) staged
        __builtin_amdgcn_sched_barrier(0);

        short8 kf[2];
        #pragma unroll
        for (int kb = 0; kb < 2; ++kb)
            kf[kb] = *(const short8*)&Kb[c * 64 + ((4 * kb + qd) ^ (c & 7)) * 8];

        __builtin_amdgcn_sched_barrier(0);

        {
            const int itn = (it + 1) & 31;
            const u16* vb = Vh + (size_t)(w * 32 + itn) * 1024 + voff;
            #pragma unroll
            for (int mt = 0; mt < 4; ++mt)
                VN[mt] = *(const short4v*)(vb + mt * 256);
        }
        {
            const int itn = (it + 2) & 31;
            const int t0n = w * 512 + itn * 16;
            const int nslot = (cur >= 1) ? cur - 1 : 2;
            u16* Kn = Kst + nslot * 1024;
            #pragma unroll
            for (int j = 0; j < 2; ++j) {
                const int row = j * 8 + krow8;
                gload_lds16(Kh + (size_t)(t0n + row) * 64 + kgc * 8,
                            Kn + j * 512 + lane * 8);
            }
        }

        f32x4 sc[4];
        #pragma unroll
        for (int qb = 0; qb < 4; ++qb) {
            sc[qb] = f32x4{0.f, 0.f, 0.f, 0.f};
            sc[qb] = __builtin_amdgcn_mfma_f32_16x16x32_bf16(kf[0], qf[qb][0], sc[qb], 0, 0, 0);
            sc[qb] = __builtin_amdgcn_mfma_f32_16x16x32_bf16(kf[1], qf[qb][1], sc[qb], 0, 0, 0);
        }

        short4v pb[4];
        #pragma unroll
        for (int qb = 0; qb < 4; ++qb) {
            float p0 = fexp2(sc[qb][0]);
            float p1 = fexp2(sc[qb][1]);
            float p2 = fexp2(sc[qb][2]);
            float p3 = fexp2(sc[qb][3]);
            lsum[qb] += (p0 + p1) + (p2 + p3);
            unsigned d0 = pack_bf16(p0, p1);
            unsigned d1 = pack_bf16(p2, p3);
            union { unsigned u[2]; short4v s; } pu;
            pu.u[0] = d0; pu.u[1] = d1;
            pb[qb] = pu.s;
        }

        #pragma unroll
        for (int qb = 0; qb < 4; ++qb)
            #pragma unroll
            for (int mt = 0; mt < 4; ++mt)
                o[mt][qb] = mfma16(VC[mt], pb[qb], o[mt][qb]);

        cur = (cur == 2) ? 0 : cur + 1;
    };

    for (int it2 = 0; it2 < 16; ++it2) {
        body(2 * it2, vA, vB);
        body(2 * it2 + 1, vB, vA);
    }

    __builtin_amdgcn_s_waitcnt(0xF70);   // vmcnt(0) before aliasing the pool
    __syncthreads();

    #pragma unroll
    for (int qb = 0; qb < 4; ++qb) {
        lsum[qb] += __shfl_xor(lsum[qb], 16, 64);
        lsum[qb] += __shfl_xor(lsum[qb], 32, 64);
    }
    if (qd == 0) {
        #pragma unroll
        for (int qb = 0; qb < 4; ++qb) Ls[w][qb * 16 + c] = lsum[qb];
    }

    if (w >= 2) {
        float (*S)[66] = Os[w - 2];
        #pragma unroll
        for (int mt = 0; mt < 4; ++mt)
            #pragma unroll
            for (int qb = 0; qb < 4; ++qb)
                #pragma unroll
                for (int r = 0; r < 4; ++r)
                    S[mt * 16 + qd * 4 + r][qb * 16 + c] = o[mt][qb][r];
    }
    __syncthreads();
    if (w < 2) {
        float (*S)[66] = Os[w];
        #pragma unroll
        for (int mt = 0; mt < 4; ++mt)
            #pragma unroll
            for (int qb = 0; qb < 4; ++qb)
                #pragma unroll
                for (int r = 0; r < 4; ++r)
                    o[mt][qb][r] += S[mt * 16 + qd * 4 + r][qb * 16 + c];
    }
    __syncthreads();
    if (w == 1) {
        float (*S)[66] = Os[0];
        #pragma unroll
        for (int mt = 0; mt < 4; ++mt)
            #pragma unroll
            for (int qb = 0; qb < 4; ++qb)
                #pragma unroll
                for (int r = 0; r < 4; ++r)
                    S[mt * 16 + qd * 4 + r][qb * 16 + c] = o[mt][qb][r];
    }
    __syncthreads();
    if (w == 0) {
        float (*S)[66] = Os[0];
        float inv[4];
        #pragma unroll
        for (int qb = 0; qb < 4; ++qb) {
            int q = qb * 16 + c;
            float l = (Ls[0][q] + Ls[1][q]) + (Ls[2][q] + Ls[3][q]);
            inv[qb] = __builtin_amdgcn_rcpf(l);
        }
        #pragma unroll
        for (int mt = 0; mt < 4; ++mt)
            #pragma unroll
            for (int qb = 0; qb < 4; ++qb) {
                u16x4 ov;
                #pragma unroll
                for (int r = 0; r < 4; ++r) {
                    float v = (o[mt][qb][r] + S[mt * 16 + qd * 4 + r][qb * 16 + c]) * inv[qb];
                    ((u16*)&ov)[r] = f2bf(v);
                }
                *(u16x4*)&ctx[((size_t)(b * 2048 + q0 + qb * 16 + c)) * 1024
                              + h * 64 + mt * 16 + qd * 4] = ov;
            }
    }
}

// ---------------- output projection: ctx[4096,1024] x Wo^T + bo, 64x128 tiles ----
__global__ __launch_bounds__(256, 4) void gemm_out_kernel(
    const u16* __restrict__ A, const u16* __restrict__ Wt,
    const float* __restrict__ bo, float* __restrict__ out)
{
    __shared__ __align__(16) u16 As[64 * 32];
    __shared__ __align__(16) u16 Bs[128 * 32];
    const int tid = threadIdx.x;
    const int lane = tid & 63;
    const int wv = tid >> 6;
    const int wm = wv & 1, wn = wv >> 1;
    const int m0 = blockIdx.x * 64;
    const int n0 = blockIdx.y * 128;
    const int c = lane & 15, qd = lane >> 4;

    f32x4 acc[2][4];
    #pragma unroll
    for (int a = 0; a < 2; ++a)
        #pragma unroll
        for (int b2 = 0; b2 < 4; ++b2) acc[a][b2] = f32x4{0.f, 0.f, 0.f, 0.f};

    const u16* Ab = A + (size_t)m0 * 1024;
    const u16* Wb = Wt + (size_t)n0 * 1024;

    for (int kt = 0; kt < 1024; kt += 32) {
        {
            int row = tid >> 2, part = tid & 3;
            gload_lds16(Ab + (size_t)row * 1024 + kt + part * 8, &As[tid * 8]);
        }
        #pragma unroll
        for (int i = 0; i < 2; ++i) {
            int slot = i * 256 + tid;
            int row = slot >> 2, part = slot & 3;
            gload_lds16(Wb + (size_t)row * 1024 + kt + part * 8, &Bs[slot * 8]);
        }
        __syncthreads();
        short8 af[2], bf[4];
        #pragma unroll
        for (int mt = 0; mt < 2; ++mt)
            af[mt] = *(const short8*)&As[(wm * 32 + mt * 16 + c) * 32 + qd * 8];
        #pragma unroll
        for (int nt = 0; nt < 4; ++nt)
            bf[nt] = *(const short8*)&Bs[(wn * 64 + nt * 16 + c) * 32 + qd * 8];
        #pragma unroll
        for (int mt = 0; mt < 2; ++mt)
            #pragma unroll
            for (int nt = 0; nt < 4; ++nt)
                acc[mt][nt] = __builtin_amdgcn_mfma_f32_16x16x32_bf16(af[mt], bf[nt], acc[mt][nt], 0, 0, 0);
        __syncthreads();
    }

    #pragma unroll
    for (int mt = 0; mt < 2; ++mt) {
        const int mbase = m0 + wm * 32 + mt * 16 + qd * 4;
        #pragma unroll
        for (int nt = 0; nt < 4; ++nt) {
            const int n = n0 + wn * 64 + nt * 16 + c;
            const float bias = bo[n];
            #pragma unroll
            for (int r = 0; r < 4; ++r)
                out[(size_t)(mbase + r) * 1024 + n] = acc[mt][nt][r] + bias;
        }
    }
}

extern "C" void kernel_launch(void* const* d_in, const int* in_sizes, int n_in,
                              void* d_out, int out_size, void* d_ws, size_t ws_size,
                              hipStream_t stream) {
    const float* x  = (const float*)d_in[0];
    const float* Wq = (const float*)d_in[1];
    const float* bq = (const float*)d_in[2];
    const float* Wk = (const float*)d_in[3];
    const float* bk = (const float*)d_in[4];
    const float* Wv = (const float*)d_in[5];
    const float* bv = (const float*)d_in[6];
    const float* Wo = (const float*)d_in[7];
    const float* bo = (const float*)d_in[8];
    float* out = (float*)d_out;

    u16* ws    = (u16*)d_ws;
    u16* xb    = ws;                          // 4096*1024
    u16* wqkv  = xb + 4096 * 1024;            // 3072*1024
    u16* wot   = wqkv + 3072 * 1024;          // 1024*1024
    u16* qws   = wot + 1024 * 1024;           // 32*2048*64
    u16* kws   = qws + 4194304;               // 32*2048*64
    u16* v2ws  = kws + 4194304;               // 32*128*64*16
    u16* ctxws = v2ws + 4194304;              // 4096*1024

    prep_kernel<<<dim3(16, 16, 5), 256, 0, stream>>>(x, Wq, Wk, Wv, Wo, xb, wqkv, wot);
    gemm_qkv_kernel<<<192, 512, 0, stream>>>(xb, wqkv, bq, bk, bv, qws, kws, v2ws);
    flash_kernel<<<1024, 256, 0, stream>>>(qws, kws, v2ws, ctxws);
    gemm_out_kernel<<<dim3(64, 8), 256, 0, stream>>>(ctxws, wot, bo, out);
}

// Round 7
// 190.667 us; speedup vs baseline: 1.1267x; 1.0225x over previous
//
#include <hip/hip_runtime.h>
#include <cstdint>

typedef unsigned short u16;
typedef __attribute__((ext_vector_type(8))) short short8;
typedef __attribute__((ext_vector_type(4))) short short4v;
typedef __attribute__((ext_vector_type(4))) float f32x4;
typedef __attribute__((ext_vector_type(4))) unsigned short u16x4;

__device__ __forceinline__ u16 f2bf(float x) {
    unsigned int u = __float_as_uint(x);
    u += 0x7fffu + ((u >> 16) & 1u);
    return (u16)(u >> 16);
}

__device__ __forceinline__ float fexp2(float x) {
#if __has_builtin(__builtin_amdgcn_exp2f)
    return __builtin_amdgcn_exp2f(x);
#else
    return exp2f(x);
#endif
}

// pack two rounded f32 -> bf16 pair in one dword (a low16, b high16) — proven path
__device__ __forceinline__ unsigned pack_bf16(float a, float b) {
    unsigned ua = __float_as_uint(a) + 0x8000u;
    unsigned ub = __float_as_uint(b) + 0x8000u;
    return __builtin_amdgcn_perm(ub, ua, 0x07060302u);
}

#if __has_builtin(__builtin_amdgcn_mfma_f32_16x16x16bf16_1k)
__device__ __forceinline__ f32x4 mfma16(short4v a, short4v b, f32x4 c) {
    return __builtin_amdgcn_mfma_f32_16x16x16bf16_1k(a, b, c, 0, 0, 0);
}
#else
__device__ __forceinline__ f32x4 mfma16(short4v a, short4v b, f32x4 c) {
    short8 a8 = {a[0], a[1], a[2], a[3], 0, 0, 0, 0};
    short8 b8 = {b[0], b[1], b[2], b[3], 0, 0, 0, 0};
    return __builtin_amdgcn_mfma_f32_16x16x32_bf16(a8, b8, c, 0, 0, 0);
}
#endif

__device__ __forceinline__ void gload_lds16(const u16* g, u16* l) {
    __builtin_amdgcn_global_load_lds(
        (const __attribute__((address_space(1))) void*)(g),
        (__attribute__((address_space(3))) void*)(l),
        16, 0, 0);
}

#define SBAR() do { __builtin_amdgcn_sched_barrier(0); \
                    __builtin_amdgcn_s_barrier(); \
                    __builtin_amdgcn_sched_barrier(0); } while (0)

// ---------------- fused prep: Wo transpose | cast x | Wq/Wk/Wv transposes ------
__global__ __launch_bounds__(256) void prep_kernel(
    const float* __restrict__ x,
    const float* __restrict__ Wq, const float* __restrict__ Wk,
    const float* __restrict__ Wv, const float* __restrict__ Wo,
    u16* __restrict__ xb, u16* __restrict__ wqkv, u16* __restrict__ wot)
{
    __shared__ u16 tile[64][65];
    const int z = blockIdx.z;
    const int tc = threadIdx.x & 63, tr = threadIdx.x >> 6;

    if (z == 1) {
        const int blk = blockIdx.y * 16 + blockIdx.x;
        const int base = (blk * 256 + threadIdx.x) * 4;
        #pragma unroll
        for (int i = 0; i < 16; ++i) {
            const int idx = base + i * 262144;
            float4 v = *(const float4*)(x + idx);
            u16x4 o;
            o.x = f2bf(v.x); o.y = f2bf(v.y); o.z = f2bf(v.z); o.w = f2bf(v.w);
            *(u16x4*)(xb + idx) = o;
        }
        return;
    }

    const float* src;
    u16* dst;
    int C, R, rb, cb;
    if (z == 0) {
        src = Wo; dst = wot; C = 1024; R = 1024;
        rb = blockIdx.x * 64; cb = blockIdx.y * 64;
    } else {
        const float* W = (z == 2) ? Wq : (z == 3) ? Wk : Wv;
        const int head = blockIdx.y;
        src = W + head * 65536;                                  // [1024][64]
        dst = wqkv + (size_t)(z - 2) * 1048576 + head * 65536;   // rows e, cols d
        C = 64; R = 1024;
        rb = blockIdx.x * 64; cb = 0;
    }
    #pragma unroll
    for (int i = 0; i < 64; i += 4)
        tile[tr + i][tc] = f2bf(src[(size_t)(rb + tr + i) * C + (cb + tc)]);
    __syncthreads();
    #pragma unroll
    for (int i = 0; i < 64; i += 4)
        dst[(size_t)(cb + tr + i) * R + (rb + tc)] = tile[tc][tr + i];
}

// ---------------- QKV GEMM v3: 256x256, BK=64, 4-phase/K-tile pipeline --------
// R5's 2-phase 256^2 hit the documented 2ph ceiling (~680 TF): critical path =
// stage+vmcnt+barrier. v3 is the m201-style schedule: per K-tile 4 phases, each
// {ds_read subtile; stage quarter-tiles of t+2; barrier; 16 MFMA (setprio);
// barrier}; counted vmcnt(8) ONCE per tile at end of Ph4 (before the closing
// barrier), never 0 until the last two gates.
// Race-freedom: quadrants Q1(mi0-3,ni0-1) Q2(mi0-3,ni2-3) Q3(mi4-7,ni2-3)
// Q4(mi4-7,ni0-1). After Ph1's closing barrier A-quarters 0,2 (rows 0-63,
// 128-191) are fully read by every wave -> staged in Ph2; after Ph2 all B is
// read -> staged in Ph3; after Ph3 A-quarters 1,3 -> staged in Ph4. Stage
// targets are disjoint from that phase's own ds_reads. Tile t+1's 8 loads are
// the oldest 8 of 16 outstanding at t's Ph4 -> vmcnt(8) there guarantees them
// landed; barrier makes that true for every wave's loads before any Ph1 read.
// Swizzle: stage chunk cg=(tid&7)^((tid>>3)&7) <-> read slot cs=kc^(c&7)
// (row&7 == c&7 on the read side) — same involution family as flash's K-ring.
// R6 fix: s_waitcnt takes a LITERAL only -> split the gate into two statically-
// constant call sites under runtime conditions.
__global__ __launch_bounds__(512, 2) void gemm_qkv_kernel(
    const u16* __restrict__ X, const u16* __restrict__ W,
    const float* __restrict__ bq, const float* __restrict__ bk,
    const float* __restrict__ bv,
    u16* __restrict__ qo, u16* __restrict__ ko, u16* __restrict__ vto)
{
    __shared__ __align__(16) u16 lds[65536];   // 128 KiB: 2 x [A 16384 | B 16384]
    const int tid = threadIdx.x;
    const int lane = tid & 63;
    const int wid = tid >> 6;            // 0..7
    const int wm = wid >> 2;             // 0..1  (128-row half)
    const int wn = wid & 3;              // 0..3  (64-col quarter)
    const int c = lane & 15, qd = lane >> 4;

    // XCD swizzle: 192 = 8 XCD x 24 (bijective).
    const int id = (blockIdx.x & 7) * 24 + (blockIdx.x >> 3);
    const int m0 = (id / 12) * 256;
    const int n0 = (id % 12) * 256;
    const u16* Xb = X + (size_t)m0 * 1024;
    const u16* Wb = W + (size_t)n0 * 1024;

    const int scg  = (tid & 7) ^ ((tid >> 3) & 7);  // staging source chunk
    const int srow = tid >> 3;                      // row within 64-row quarter
    const int co0 = (qd ^ (c & 7)) * 8;             // read chunk offset, ks=0
    const int co1 = ((4 + qd) ^ (c & 7)) * 8;       // ks=1
    const int rA = wm * 128 + c;
    const int rB = wn * 64 + c;

    auto stageA = [&](int t, int qa) {   // A quarter qa: rows [qa*64, qa*64+64)
        const int pb = (t & 1) * 32768;
        gload_lds16(Xb + (size_t)(qa * 64 + srow) * 1024 + t * 64 + scg * 8,
                    &lds[pb + (qa * 512 + tid) * 8]);
    };
    auto stageB = [&](int t, int qb) {
        const int pb = (t & 1) * 32768;
        gload_lds16(Wb + (size_t)(qb * 64 + srow) * 1024 + t * 64 + scg * 8,
                    &lds[pb + 16384 + (qb * 512 + tid) * 8]);
    };

    f32x4 acc[8][4];
    #pragma unroll
    for (int mi = 0; mi < 8; ++mi)
        #pragma unroll
        for (int ni = 0; ni < 4; ++ni) acc[mi][ni] = f32x4{0.f, 0.f, 0.f, 0.f};

    // prologue: all 8 quarters of tile 0, then tile 1
    #pragma unroll
    for (int q = 0; q < 4; ++q) stageA(0, q);
    #pragma unroll
    for (int q = 0; q < 4; ++q) stageB(0, q);
    #pragma unroll
    for (int q = 0; q < 4; ++q) stageA(1, q);
    #pragma unroll
    for (int q = 0; q < 4; ++q) stageB(1, q);
    __builtin_amdgcn_s_waitcnt(0xF78);   // vmcnt(8): tile 0's 8 landed
    SBAR();

    #pragma unroll 2
    for (int t = 0; t < 16; ++t) {
        const int pb = (t & 1) * 32768;
        const u16* Al = &lds[pb];
        const u16* Bl = &lds[pb + 16384];

        // ---- Phase 1: read af0(mi0-3), bf0(ni0-1); MFMA Q1
        short8 af0[4][2], bf0[2][2];
        #pragma unroll
        for (int mi = 0; mi < 4; ++mi) {
            af0[mi][0] = *(const short8*)&Al[(rA + mi * 16) * 64 + co0];
            af0[mi][1] = *(const short8*)&Al[(rA + mi * 16) * 64 + co1];
        }
        #pragma unroll
        for (int ni = 0; ni < 2; ++ni) {
            bf0[ni][0] = *(const short8*)&Bl[(rB + ni * 16) * 64 + co0];
            bf0[ni][1] = *(const short8*)&Bl[(rB + ni * 16) * 64 + co1];
        }
        SBAR();
        __builtin_amdgcn_s_setprio(1);
        #pragma unroll
        for (int mi = 0; mi < 4; ++mi)
            #pragma unroll
            for (int ni = 0; ni < 2; ++ni) {
                acc[mi][ni] = __builtin_amdgcn_mfma_f32_16x16x32_bf16(af0[mi][0], bf0[ni][0], acc[mi][ni], 0, 0, 0);
                acc[mi][ni] = __builtin_amdgcn_mfma_f32_16x16x32_bf16(af0[mi][1], bf0[ni][1], acc[mi][ni], 0, 0, 0);
            }
        __builtin_amdgcn_s_setprio(0);
        SBAR();

        // ---- Phase 2: read bf1(ni2-3); stage A q0,q2 of t+2; MFMA Q2
        short8 bf1[2][2];
        #pragma unroll
        for (int ni = 0; ni < 2; ++ni) {
            bf1[ni][0] = *(const short8*)&Bl[(rB + (ni + 2) * 16) * 64 + co0];
            bf1[ni][1] = *(const short8*)&Bl[(rB + (ni + 2) * 16) * 64 + co1];
        }
        if (t < 14) { stageA(t + 2, 0); stageA(t + 2, 2); }
        SBAR();
        __builtin_amdgcn_s_setprio(1);
        #pragma unroll
        for (int mi = 0; mi < 4; ++mi)
            #pragma unroll
            for (int ni = 0; ni < 2; ++ni) {
                acc[mi][ni + 2] = __builtin_amdgcn_mfma_f32_16x16x32_bf16(af0[mi][0], bf1[ni][0], acc[mi][ni + 2], 0, 0, 0);
                acc[mi][ni + 2] = __builtin_amdgcn_mfma_f32_16x16x32_bf16(af0[mi][1], bf1[ni][1], acc[mi][ni + 2], 0, 0, 0);
            }
        __builtin_amdgcn_s_setprio(0);
        SBAR();

        // ---- Phase 3: read af1(mi4-7); stage B q0-3 of t+2; MFMA Q3
        short8 af1[4][2];
        #pragma unroll
        for (int mi = 0; mi < 4; ++mi) {
            af1[mi][0] = *(const short8*)&Al[(rA + (mi + 4) * 16) * 64 + co0];
            af1[mi][1] = *(const short8*)&Al[(rA + (mi + 4) * 16) * 64 + co1];
        }
        if (t < 14) { stageB(t + 2, 0); stageB(t + 2, 1); stageB(t + 2, 2); stageB(t + 2, 3); }
        SBAR();
        __builtin_amdgcn_s_setprio(1);
        #pragma unroll
        for (int mi = 0; mi < 4; ++mi)
            #pragma unroll
            for (int ni = 0; ni < 2; ++ni) {
                acc[mi + 4][ni + 2] = __builtin_amdgcn_mfma_f32_16x16x32_bf16(af1[mi][0], bf1[ni][0], acc[mi + 4][ni + 2], 0, 0, 0);
                acc[mi + 4][ni + 2] = __builtin_amdgcn_mfma_f32_16x16x32_bf16(af1[mi][1], bf1[ni][1], acc[mi + 4][ni + 2], 0, 0, 0);
            }
        __builtin_amdgcn_s_setprio(0);
        SBAR();

        // ---- Phase 4: stage A q1,q3 of t+2; MFMA Q4; per-tile vmcnt gate
        if (t < 14) { stageA(t + 2, 1); stageA(t + 2, 3); }
        SBAR();
        __builtin_amdgcn_s_setprio(1);
        #pragma unroll
        for (int mi = 0; mi < 4; ++mi)
            #pragma unroll
            for (int ni = 0; ni < 2; ++ni) {
                acc[mi + 4][ni] = __builtin_amdgcn_mfma_f32_16x16x32_bf16(af1[mi][0], bf0[ni][0], acc[mi + 4][ni], 0, 0, 0);
                acc[mi + 4][ni] = __builtin_amdgcn_mfma_f32_16x16x32_bf16(af1[mi][1], bf0[ni][1], acc[mi + 4][ni], 0, 0, 0);
            }
        __builtin_amdgcn_s_setprio(0);
        // gate tile t+1 (literal-only builtin: two constant call sites)
        if (t < 14)       __builtin_amdgcn_s_waitcnt(0xF78);   // vmcnt(8)
        else if (t == 14) __builtin_amdgcn_s_waitcnt(0xF70);   // vmcnt(0): last tile
        SBAR();
    }

    // epilogue: n -> (mat, h, e); m -> (b, s)   [proven mapping, R5]
    #pragma unroll
    for (int mi = 0; mi < 8; ++mi) {
        const int mbase = m0 + wm * 128 + mi * 16 + qd * 4;
        const int b = mbase >> 11;
        #pragma unroll
        for (int ni = 0; ni < 4; ++ni) {
            const int n = n0 + wn * 64 + ni * 16 + c;
            const int mat = n >> 10;
            const int idx = n & 1023;
            const int h = idx >> 6, e = idx & 63;
            const float bias = (mat == 0 ? bq : (mat == 1 ? bk : bv))[idx];
            if (mat == 2) {
                const int s = mbase & 2047;
                u16x4 pv;
                pv.x = f2bf(acc[mi][ni][0] + bias);
                pv.y = f2bf(acc[mi][ni][1] + bias);
                pv.z = f2bf(acc[mi][ni][2] + bias);
                pv.w = f2bf(acc[mi][ni][3] + bias);
                *(u16x4*)(vto + ((((size_t)(b * 16 + h) * 128 + (s >> 4)) * 64 + e) * 16
                                 + (s & 15))) = pv;
            } else {
                const float scale = (mat == 0) ? 0.18033688011112042f : 1.0f;
                u16* dst = (mat == 0) ? qo : ko;
                #pragma unroll
                for (int r = 0; r < 4; ++r) {
                    const int s = (mbase + r) & 2047;
                    dst[((size_t)((b * 16 + h) * 2048 + s)) * 64 + e] =
                        f2bf((acc[mi][ni][r] + bias) * scale);
                }
            }
        }
    }
}

// ---------------- flash attention v8 (proven 53.4-54.5 us, verbatim) ----------
__global__ __launch_bounds__(256, 3) void flash_kernel(
    const u16* __restrict__ Q,   // [32][2048][64], pre-scaled by 0.125*log2e
    const u16* __restrict__ K,   // [32][2048][64]
    const u16* __restrict__ V2,  // [32][128][64][16]
    u16* __restrict__ ctx)       // [4096][1024] = [b*2048+s][h*64+e]
{
    __shared__ __align__(16) char pool[34816];
    u16* stage = (u16*)pool;                              // K ring-3: 4w*3072 u16
    float (*Os)[64][66] = (float (*)[64][66])pool;        // merge (aliased)
    float (*Ls)[64] = (float (*)[64])(pool + 33792);      // 1 KB

    const int tid = threadIdx.x, lane = tid & 63, w = tid >> 6;
    const int c = lane & 15, qd = lane >> 4;
    const int bid = blockIdx.x;
    const int r5 = bid & 31;
    const int bh = (r5 & 7) * 4 + (r5 >> 3);   // pin each bh's blocks to one XCD
    const int q0 = (bid >> 5) * 64;
    const int b = bh >> 4, h = bh & 15;
    const u16* Qh = Q + (size_t)bh * 2048 * 64;
    const u16* Kh = K + (size_t)bh * 2048 * 64;
    const u16* Vh = V2 + (size_t)bh * 128 * 1024;

    u16* Kst = stage + w * 3072;             // 3 K slots x 1024 u16

    const int krow8 = lane >> 3;
    const int kgc = (lane & 7) ^ (krow8 & 7);
    const int voff = c * 16 + qd * 4;

    short8 qf[4][2];
    #pragma unroll
    for (int qb = 0; qb < 4; ++qb)
        #pragma unroll
        for (int kb = 0; kb < 2; ++kb)
            qf[qb][kb] = *(const short8*)&Qh[(size_t)(q0 + qb * 16 + c) * 64 + kb * 32 + qd * 8];

    f32x4 o[4][4];
    float lsum[4];
    #pragma unroll
    for (int mt = 0; mt < 4; ++mt)
        #pragma unroll
        for (int qb = 0; qb < 4; ++qb) o[mt][qb] = f32x4{0.f, 0.f, 0.f, 0.f};
    #pragma unroll
    for (int qb = 0; qb < 4; ++qb) lsum[qb] = 0.f;

    #pragma unroll
    for (int j = 0; j < 2; ++j) {
        const int row = j * 8 + krow8;
        gload_lds16(Kh + (size_t)(w * 512 + row) * 64 + kgc * 8,
                    Kst + j * 512 + lane * 8);
    }
    short4v vA[4], vB[4];
    {
        const u16* vb = Vh + (size_t)(w * 32) * 1024 + voff;
        #pragma unroll
        for (int mt = 0; mt < 4; ++mt)
            vA[mt] = *(const short4v*)(vb + mt * 256);
    }
    #pragma unroll
    for (int j = 0; j < 2; ++j) {
        const int row = j * 8 + krow8;
        gload_lds16(Kh + (size_t)(w * 512 + 16 + row) * 64 + kgc * 8,
                    Kst + 1024 + j * 512 + lane * 8);
    }

    int cur = 0;
    auto body = [&](int it, short4v (&VC)[4], short4v (&VN)[4]) {
        u16* Kb = Kst + cur * 1024;

        __builtin_amdgcn_s_waitcnt(0xF74);   // vmcnt(4): K(it) staged
        __builtin_amdgcn_sched_barrier(0);

        short8 kf[2];
        #pragma unroll
        for (int kb = 0; kb < 2; ++kb)
            kf[kb] = *(const short8*)&Kb[c * 64 + ((4 * kb + qd) ^ (c & 7)) * 8];

        __builtin_amdgcn_sched_barrier(0);

        {
            const int itn = (it + 1) & 31;
            const u16* vb = Vh + (size_t)(w * 32 + itn) * 1024 + voff;
            #pragma unroll
            for (int mt = 0; mt < 4; ++mt)
                VN[mt] = *(const short4v*)(vb + mt * 256);
        }
        {
            const int itn = (it + 2) & 31;
            const int t0n = w * 512 + itn * 16;
            const int nslot = (cur >= 1) ? cur - 1 : 2;
            u16* Kn = Kst + nslot * 1024;
            #pragma unroll
            for (int j = 0; j < 2; ++j) {
                const int row = j * 8 + krow8;
                gload_lds16(Kh + (size_t)(t0n + row) * 64 + kgc * 8,
                            Kn + j * 512 + lane * 8);
            }
        }

        f32x4 sc[4];
        #pragma unroll
        for (int qb = 0; qb < 4; ++qb) {
            sc[qb] = f32x4{0.f, 0.f, 0.f, 0.f};
            sc[qb] = __builtin_amdgcn_mfma_f32_16x16x32_bf16(kf[0], qf[qb][0], sc[qb], 0, 0, 0);
            sc[qb] = __builtin_amdgcn_mfma_f32_16x16x32_bf16(kf[1], qf[qb][1], sc[qb], 0, 0, 0);
        }

        short4v pb[4];
        #pragma unroll
        for (int qb = 0; qb < 4; ++qb) {
            float p0 = fexp2(sc[qb][0]);
            float p1 = fexp2(sc[qb][1]);
            float p2 = fexp2(sc[qb][2]);
            float p3 = fexp2(sc[qb][3]);
            lsum[qb] += (p0 + p1) + (p2 + p3);
            unsigned d0 = pack_bf16(p0, p1);
            unsigned d1 = pack_bf16(p2, p3);
            union { unsigned u[2]; short4v s; } pu;
            pu.u[0] = d0; pu.u[1] = d1;
            pb[qb] = pu.s;
        }

        #pragma unroll
        for (int qb = 0; qb < 4; ++qb)
            #pragma unroll
            for (int mt = 0; mt < 4; ++mt)
                o[mt][qb] = mfma16(VC[mt], pb[qb], o[mt][qb]);

        cur = (cur == 2) ? 0 : cur + 1;
    };

    for (int it2 = 0; it2 < 16; ++it2) {
        body(2 * it2, vA, vB);
        body(2 * it2 + 1, vB, vA);
    }

    __builtin_amdgcn_s_waitcnt(0xF70);   // vmcnt(0) before aliasing the pool
    __syncthreads();

    #pragma unroll
    for (int qb = 0; qb < 4; ++qb) {
        lsum[qb] += __shfl_xor(lsum[qb], 16, 64);
        lsum[qb] += __shfl_xor(lsum[qb], 32, 64);
    }
    if (qd == 0) {
        #pragma unroll
        for (int qb = 0; qb < 4; ++qb) Ls[w][qb * 16 + c] = lsum[qb];
    }

    if (w >= 2) {
        float (*S)[66] = Os[w - 2];
        #pragma unroll
        for (int mt = 0; mt < 4; ++mt)
            #pragma unroll
            for (int qb = 0; qb < 4; ++qb)
                #pragma unroll
                for (int r = 0; r < 4; ++r)
                    S[mt * 16 + qd * 4 + r][qb * 16 + c] = o[mt][qb][r];
    }
    __syncthreads();
    if (w < 2) {
        float (*S)[66] = Os[w];
        #pragma unroll
        for (int mt = 0; mt < 4; ++mt)
            #pragma unroll
            for (int qb = 0; qb < 4; ++qb)
                #pragma unroll
                for (int r = 0; r < 4; ++r)
                    o[mt][qb][r] += S[mt * 16 + qd * 4 + r][qb * 16 + c];
    }
    __syncthreads();
    if (w == 1) {
        float (*S)[66] = Os[0];
        #pragma unroll
        for (int mt = 0; mt < 4; ++mt)
            #pragma unroll
            for (int qb = 0; qb < 4; ++qb)
                #pragma unroll
                for (int r = 0; r < 4; ++r)
                    S[mt * 16 + qd * 4 + r][qb * 16 + c] = o[mt][qb][r];
    }
    __syncthreads();
    if (w == 0) {
        float (*S)[66] = Os[0];
        float inv[4];
        #pragma unroll
        for (int qb = 0; qb < 4; ++qb) {
            int q = qb * 16 + c;
            float l = (Ls[0][q] + Ls[1][q]) + (Ls[2][q] + Ls[3][q]);
            inv[qb] = __builtin_amdgcn_rcpf(l);
        }
        #pragma unroll
        for (int mt = 0; mt < 4; ++mt)
            #pragma unroll
            for (int qb = 0; qb < 4; ++qb) {
                u16x4 ov;
                #pragma unroll
                for (int r = 0; r < 4; ++r) {
                    float v = (o[mt][qb][r] + S[mt * 16 + qd * 4 + r][qb * 16 + c]) * inv[qb];
                    ((u16*)&ov)[r] = f2bf(v);
                }
                *(u16x4*)&ctx[((size_t)(b * 2048 + q0 + qb * 16 + c)) * 1024
                              + h * 64 + mt * 16 + qd * 4] = ov;
            }
    }
}

// ---------------- output projection: ctx[4096,1024] x Wo^T + bo, 64x128 tiles ----
__global__ __launch_bounds__(256, 4) void gemm_out_kernel(
    const u16* __restrict__ A, const u16* __restrict__ Wt,
    const float* __restrict__ bo, float* __restrict__ out)
{
    __shared__ __align__(16) u16 As[64 * 32];
    __shared__ __align__(16) u16 Bs[128 * 32];
    const int tid = threadIdx.x;
    const int lane = tid & 63;
    const int wv = tid >> 6;
    const int wm = wv & 1, wn = wv >> 1;
    const int m0 = blockIdx.x * 64;
    const int n0 = blockIdx.y * 128;
    const int c = lane & 15, qd = lane >> 4;

    f32x4 acc[2][4];
    #pragma unroll
    for (int a = 0; a < 2; ++a)
        #pragma unroll
        for (int b2 = 0; b2 < 4; ++b2) acc[a][b2] = f32x4{0.f, 0.f, 0.f, 0.f};

    const u16* Ab = A + (size_t)m0 * 1024;
    const u16* Wb = Wt + (size_t)n0 * 1024;

    for (int kt = 0; kt < 1024; kt += 32) {
        {
            int row = tid >> 2, part = tid & 3;
            gload_lds16(Ab + (size_t)row * 1024 + kt + part * 8, &As[tid * 8]);
        }
        #pragma unroll
        for (int i = 0; i < 2; ++i) {
            int slot = i * 256 + tid;
            int row = slot >> 2, part = slot & 3;
            gload_lds16(Wb + (size_t)row * 1024 + kt + part * 8, &Bs[slot * 8]);
        }
        __syncthreads();
        short8 af[2], bf[4];
        #pragma unroll
        for (int mt = 0; mt < 2; ++mt)
            af[mt] = *(const short8*)&As[(wm * 32 + mt * 16 + c) * 32 + qd * 8];
        #pragma unroll
        for (int nt = 0; nt < 4; ++nt)
            bf[nt] = *(const short8*)&Bs[(wn * 64 + nt * 16 + c) * 32 + qd * 8];
        #pragma unroll
        for (int mt = 0; mt < 2; ++mt)
            #pragma unroll
            for (int nt = 0; nt < 4; ++nt)
                acc[mt][nt] = __builtin_amdgcn_mfma_f32_16x16x32_bf16(af[mt], bf[nt], acc[mt][nt], 0, 0, 0);
        __syncthreads();
    }

    #pragma unroll
    for (int mt = 0; mt < 2; ++mt) {
        const int mbase = m0 + wm * 32 + mt * 16 + qd * 4;
        #pragma unroll
        for (int nt = 0; nt < 4; ++nt) {
            const int n = n0 + wn * 64 + nt * 16 + c;
            const float bias = bo[n];
            #pragma unroll
            for (int r = 0; r < 4; ++r)
                out[(size_t)(mbase + r) * 1024 + n] = acc[mt][nt][r] + bias;
        }
    }
}

extern "C" void kernel_launch(void* const* d_in, const int* in_sizes, int n_in,
                              void* d_out, int out_size, void* d_ws, size_t ws_size,
                              hipStream_t stream) {
    const float* x  = (const float*)d_in[0];
    const float* Wq = (const float*)d_in[1];
    const float* bq = (const float*)d_in[2];
    const float* Wk = (const float*)d_in[3];
    const float* bk = (const float*)d_in[4];
    const float* Wv = (const float*)d_in[5];
    const float* bv = (const float*)d_in[6];
    const float* Wo = (const float*)d_in[7];
    const float* bo = (const float*)d_in[8];
    float* out = (float*)d_out;

    u16* ws    = (u16*)d_ws;
    u16* xb    = ws;                          // 4096*1024
    u16* wqkv  = xb + 4096 * 1024;            // 3072*1024
    u16* wot   = wqkv + 3072 * 1024;          // 1024*1024
    u16* qws   = wot + 1024 * 1024;           // 32*2048*64
    u16* kws   = qws + 4194304;               // 32*2048*64
    u16* v2ws  = kws + 4194304;               // 32*128*64*16
    u16* ctxws = v2ws + 4194304;              // 4096*1024

    prep_kernel<<<dim3(16, 16, 5), 256, 0, stream>>>(x, Wq, Wk, Wv, Wo, xb, wqkv, wot);
    gemm_qkv_kernel<<<192, 512, 0, stream>>>(xb, wqkv, bq, bk, bv, qws, kws, v2ws);
    flash_kernel<<<1024, 256, 0, stream>>>(qws, kws, v2ws, ctxws);
    gemm_out_kernel<<<dim3(64, 8), 256, 0, stream>>>(ctxws, wot, bo, out);
}

// Round 8
// 188.669 us; speedup vs baseline: 1.1387x; 1.0106x over previous
//
#include <hip/hip_runtime.h>
#include <cstdint>

typedef unsigned short u16;
typedef __attribute__((ext_vector_type(8))) short short8;
typedef __attribute__((ext_vector_type(4))) short short4v;
typedef __attribute__((ext_vector_type(4))) float f32x4;
typedef __attribute__((ext_vector_type(4))) unsigned short u16x4;

__device__ __forceinline__ u16 f2bf(float x) {
    unsigned int u = __float_as_uint(x);
    u += 0x7fffu + ((u >> 16) & 1u);
    return (u16)(u >> 16);
}

__device__ __forceinline__ float fexp2(float x) {
#if __has_builtin(__builtin_amdgcn_exp2f)
    return __builtin_amdgcn_exp2f(x);
#else
    return exp2f(x);
#endif
}

// pack two rounded f32 -> bf16 pair in one dword (a low16, b high16) — proven path
__device__ __forceinline__ unsigned pack_bf16(float a, float b) {
    unsigned ua = __float_as_uint(a) + 0x8000u;
    unsigned ub = __float_as_uint(b) + 0x8000u;
    return __builtin_amdgcn_perm(ub, ua, 0x07060302u);
}

#if __has_builtin(__builtin_amdgcn_mfma_f32_16x16x16bf16_1k)
__device__ __forceinline__ f32x4 mfma16(short4v a, short4v b, f32x4 c) {
    return __builtin_amdgcn_mfma_f32_16x16x16bf16_1k(a, b, c, 0, 0, 0);
}
#else
__device__ __forceinline__ f32x4 mfma16(short4v a, short4v b, f32x4 c) {
    short8 a8 = {a[0], a[1], a[2], a[3], 0, 0, 0, 0};
    short8 b8 = {b[0], b[1], b[2], b[3], 0, 0, 0, 0};
    return __builtin_amdgcn_mfma_f32_16x16x32_bf16(a8, b8, c, 0, 0, 0);
}
#endif

__device__ __forceinline__ void gload_lds16(const u16* g, u16* l) {
    __builtin_amdgcn_global_load_lds(
        (const __attribute__((address_space(1))) void*)(g),
        (__attribute__((address_space(3))) void*)(l),
        16, 0, 0);
}

#define SBAR() do { __builtin_amdgcn_sched_barrier(0); \
                    __builtin_amdgcn_s_barrier(); \
                    __builtin_amdgcn_sched_barrier(0); } while (0)

// ---------------- fused prep: Wo transpose | cast x | Wq/Wk/Wv transposes ------
__global__ __launch_bounds__(256) void prep_kernel(
    const float* __restrict__ x,
    const float* __restrict__ Wq, const float* __restrict__ Wk,
    const float* __restrict__ Wv, const float* __restrict__ Wo,
    u16* __restrict__ xb, u16* __restrict__ wqkv, u16* __restrict__ wot)
{
    __shared__ u16 tile[64][65];
    const int z = blockIdx.z;
    const int tc = threadIdx.x & 63, tr = threadIdx.x >> 6;

    if (z == 1) {
        const int blk = blockIdx.y * 16 + blockIdx.x;
        const int base = (blk * 256 + threadIdx.x) * 4;
        #pragma unroll
        for (int i = 0; i < 16; ++i) {
            const int idx = base + i * 262144;
            float4 v = *(const float4*)(x + idx);
            u16x4 o;
            o.x = f2bf(v.x); o.y = f2bf(v.y); o.z = f2bf(v.z); o.w = f2bf(v.w);
            *(u16x4*)(xb + idx) = o;
        }
        return;
    }

    const float* src;
    u16* dst;
    int C, R, rb, cb;
    if (z == 0) {
        src = Wo; dst = wot; C = 1024; R = 1024;
        rb = blockIdx.x * 64; cb = blockIdx.y * 64;
    } else {
        const float* W = (z == 2) ? Wq : (z == 3) ? Wk : Wv;
        const int head = blockIdx.y;
        src = W + head * 65536;                                  // [1024][64]
        dst = wqkv + (size_t)(z - 2) * 1048576 + head * 65536;   // rows e, cols d
        C = 64; R = 1024;
        rb = blockIdx.x * 64; cb = 0;
    }
    #pragma unroll
    for (int i = 0; i < 64; i += 4)
        tile[tr + i][tc] = f2bf(src[(size_t)(rb + tr + i) * C + (cb + tc)]);
    __syncthreads();
    #pragma unroll
    for (int i = 0; i < 64; i += 4)
        dst[(size_t)(cb + tr + i) * R + (rb + tc)] = tile[tc][tr + i];
}

// ---------------- QKV GEMM v4: 256x192 tile, BK=64, 3-phase, 256 blocks -------
// R7 (256x256, 192 blocks) proved the phased counted-vmcnt pipeline but ran on
// 75% of the machine (192/256 CUs at 1 block/CU). v4 keeps the proven schedule
// and reshapes to 256x192 -> grid 16x16 = 256 blocks = every CU busy.
// LDS 112 KiB: 2 x (A 256x64 | B 192x64) bf16, XOR chunk-swizzled (R7-proven).
// Region-freeing invariant (R7-proven): a sub-tile is stageable once all its
// ds_reads completed; each fragment is MFMA-consumed in the phase it is read
// (lgkmcnt forced) before that phase's closing barrier.
//  P1: read af0(8)+bf01(4);                bar; 16 MFMA af0x{bf0,bf1}; bar.
//  P2: read af1(8)+bf2(2); stage A q0,q2;  bar; 16 MFMA af0xbf2,af1xbf0; bar.
//  P3: stage A q1,q3 + B q0,q1,q2;         bar; 16 MFMA af1x{bf1,bf2};
//      gate vmcnt(7) [t+1's 7 loads oldest of 14] / vmcnt(0) at t==14; bar.
// Epilogue is fully per-element (mat = n>>10) so 192-wide tiles straddling the
// Q/K/V boundaries are handled unchanged.
__global__ __launch_bounds__(512, 2) void gemm_qkv_kernel(
    const u16* __restrict__ X, const u16* __restrict__ W,
    const float* __restrict__ bq, const float* __restrict__ bk,
    const float* __restrict__ bv,
    u16* __restrict__ qo, u16* __restrict__ ko, u16* __restrict__ vto)
{
    __shared__ __align__(16) u16 lds[57344];   // 112 KiB: 2 x [A 16384 | B 12288]
    const int tid = threadIdx.x;
    const int lane = tid & 63;
    const int wid = tid >> 6;            // 0..7
    const int wm = wid >> 2;             // 0..1  (128-row half)
    const int wn = wid & 3;              // 0..3  (48-col quarter)
    const int c = lane & 15, qd = lane >> 4;

    // XCD swizzle: grp = bid&7 owns mt in [(grp>>1)*4,+4) x nt in [(grp&1)*8,+8)
    // -> per-XCD working set: X 4 panels (2MB) + W 8 panels (3MB) ~ L2-sized.
    const int grp = blockIdx.x & 7, k = blockIdx.x >> 3;
    const int m0 = ((grp >> 1) * 4 + (k >> 3)) * 256;
    const int n0 = ((grp & 1) * 8 + (k & 7)) * 192;
    const u16* Xb = X + (size_t)m0 * 1024;
    const u16* Wb = W + (size_t)n0 * 1024;

    const int scg  = (tid & 7) ^ ((tid >> 3) & 7);  // staging source chunk
    const int srow = tid >> 3;                      // row within 64-row quarter
    const int co0 = (qd ^ (c & 7)) * 8;             // read chunk offset, ks=0
    const int co1 = ((4 + qd) ^ (c & 7)) * 8;       // ks=1
    const int rA = wm * 128 + c;
    const int rB = wn * 48 + c;

    auto stageA = [&](int t, int qa) {   // A quarter qa: rows [qa*64, qa*64+64)
        const int pb = (t & 1) * 28672;
        gload_lds16(Xb + (size_t)(qa * 64 + srow) * 1024 + t * 64 + scg * 8,
                    &lds[pb + (qa * 512 + tid) * 8]);
    };
    auto stageB = [&](int t, int qb) {   // B third qb: rows [qb*64, qb*64+64)
        const int pb = (t & 1) * 28672;
        gload_lds16(Wb + (size_t)(qb * 64 + srow) * 1024 + t * 64 + scg * 8,
                    &lds[pb + 16384 + (qb * 512 + tid) * 8]);
    };

    f32x4 acc[8][3];
    #pragma unroll
    for (int mi = 0; mi < 8; ++mi)
        #pragma unroll
        for (int ni = 0; ni < 3; ++ni) acc[mi][ni] = f32x4{0.f, 0.f, 0.f, 0.f};

    // prologue: tile 0 (7 loads), tile 1 (7 loads)
    #pragma unroll
    for (int q = 0; q < 4; ++q) stageA(0, q);
    #pragma unroll
    for (int q = 0; q < 3; ++q) stageB(0, q);
    #pragma unroll
    for (int q = 0; q < 4; ++q) stageA(1, q);
    #pragma unroll
    for (int q = 0; q < 3; ++q) stageB(1, q);
    __builtin_amdgcn_s_waitcnt(0xF77);   // vmcnt(7): tile 0's 7 landed
    SBAR();

    #pragma unroll 2
    for (int t = 0; t < 16; ++t) {
        const int pb = (t & 1) * 28672;
        const u16* Al = &lds[pb];
        const u16* Bl = &lds[pb + 16384];

        // ---- Phase 1: read af0(mi0-3), bf0,bf1(ni0-1); MFMA af0 x {bf0,bf1}
        short8 af0[4][2], bf[3][2];
        #pragma unroll
        for (int mi = 0; mi < 4; ++mi) {
            af0[mi][0] = *(const short8*)&Al[(rA + mi * 16) * 64 + co0];
            af0[mi][1] = *(const short8*)&Al[(rA + mi * 16) * 64 + co1];
        }
        #pragma unroll
        for (int ni = 0; ni < 2; ++ni) {
            bf[ni][0] = *(const short8*)&Bl[(rB + ni * 16) * 64 + co0];
            bf[ni][1] = *(const short8*)&Bl[(rB + ni * 16) * 64 + co1];
        }
        SBAR();
        __builtin_amdgcn_s_setprio(1);
        #pragma unroll
        for (int mi = 0; mi < 4; ++mi)
            #pragma unroll
            for (int ni = 0; ni < 2; ++ni) {
                acc[mi][ni] = __builtin_amdgcn_mfma_f32_16x16x32_bf16(af0[mi][0], bf[ni][0], acc[mi][ni], 0, 0, 0);
                acc[mi][ni] = __builtin_amdgcn_mfma_f32_16x16x32_bf16(af0[mi][1], bf[ni][1], acc[mi][ni], 0, 0, 0);
            }
        __builtin_amdgcn_s_setprio(0);
        SBAR();

        // ---- Phase 2: read af1(mi4-7), bf2(ni2); stage A q0,q2 of t+2;
        //               MFMA af0 x bf2, af1 x bf0
        short8 af1[4][2];
        #pragma unroll
        for (int mi = 0; mi < 4; ++mi) {
            af1[mi][0] = *(const short8*)&Al[(rA + (mi + 4) * 16) * 64 + co0];
            af1[mi][1] = *(const short8*)&Al[(rA + (mi + 4) * 16) * 64 + co1];
        }
        bf[2][0] = *(const short8*)&Bl[(rB + 2 * 16) * 64 + co0];
        bf[2][1] = *(const short8*)&Bl[(rB + 2 * 16) * 64 + co1];
        if (t < 14) { stageA(t + 2, 0); stageA(t + 2, 2); }
        SBAR();
        __builtin_amdgcn_s_setprio(1);
        #pragma unroll
        for (int mi = 0; mi < 4; ++mi) {
            acc[mi][2] = __builtin_amdgcn_mfma_f32_16x16x32_bf16(af0[mi][0], bf[2][0], acc[mi][2], 0, 0, 0);
            acc[mi][2] = __builtin_amdgcn_mfma_f32_16x16x32_bf16(af0[mi][1], bf[2][1], acc[mi][2], 0, 0, 0);
        }
        #pragma unroll
        for (int mi = 0; mi < 4; ++mi) {
            acc[mi + 4][0] = __builtin_amdgcn_mfma_f32_16x16x32_bf16(af1[mi][0], bf[0][0], acc[mi + 4][0], 0, 0, 0);
            acc[mi + 4][0] = __builtin_amdgcn_mfma_f32_16x16x32_bf16(af1[mi][1], bf[0][1], acc[mi + 4][0], 0, 0, 0);
        }
        __builtin_amdgcn_s_setprio(0);
        SBAR();

        // ---- Phase 3: stage A q1,q3 + B q0,q1,q2 of t+2; MFMA af1 x {bf1,bf2}
        if (t < 14) {
            stageA(t + 2, 1); stageA(t + 2, 3);
            stageB(t + 2, 0); stageB(t + 2, 1); stageB(t + 2, 2);
        }
        SBAR();
        __builtin_amdgcn_s_setprio(1);
        #pragma unroll
        for (int mi = 0; mi < 4; ++mi)
            #pragma unroll
            for (int ni = 1; ni < 3; ++ni) {
                acc[mi + 4][ni] = __builtin_amdgcn_mfma_f32_16x16x32_bf16(af1[mi][0], bf[ni][0], acc[mi + 4][ni], 0, 0, 0);
                acc[mi + 4][ni] = __builtin_amdgcn_mfma_f32_16x16x32_bf16(af1[mi][1], bf[ni][1], acc[mi + 4][ni], 0, 0, 0);
            }
        __builtin_amdgcn_s_setprio(0);
        // gate tile t+1 (literal-only builtin: constant call sites)
        if (t < 14)       __builtin_amdgcn_s_waitcnt(0xF77);   // vmcnt(7)
        else if (t == 14) __builtin_amdgcn_s_waitcnt(0xF70);   // vmcnt(0): last
        SBAR();
    }

    // epilogue: n -> (mat, h, e); m -> (b, s)   [proven per-element mapping]
    #pragma unroll
    for (int mi = 0; mi < 8; ++mi) {
        const int mbase = m0 + wm * 128 + mi * 16 + qd * 4;
        const int b = mbase >> 11;
        #pragma unroll
        for (int ni = 0; ni < 3; ++ni) {
            const int n = n0 + wn * 48 + ni * 16 + c;
            const int mat = n >> 10;
            const int idx = n & 1023;
            const int h = idx >> 6, e = idx & 63;
            const float bias = (mat == 0 ? bq : (mat == 1 ? bk : bv))[idx];
            if (mat == 2) {
                const int s = mbase & 2047;
                u16x4 pv;
                pv.x = f2bf(acc[mi][ni][0] + bias);
                pv.y = f2bf(acc[mi][ni][1] + bias);
                pv.z = f2bf(acc[mi][ni][2] + bias);
                pv.w = f2bf(acc[mi][ni][3] + bias);
                *(u16x4*)(vto + ((((size_t)(b * 16 + h) * 128 + (s >> 4)) * 64 + e) * 16
                                 + (s & 15))) = pv;
            } else {
                const float scale = (mat == 0) ? 0.18033688011112042f : 1.0f;
                u16* dst = (mat == 0) ? qo : ko;
                #pragma unroll
                for (int r = 0; r < 4; ++r) {
                    const int s = (mbase + r) & 2047;
                    dst[((size_t)((b * 16 + h) * 2048 + s)) * 64 + e] =
                        f2bf((acc[mi][ni][r] + bias) * scale);
                }
            }
        }
    }
}

// ---------------- flash attention v8 (proven 53.4-54.6 us, verbatim) ----------
__global__ __launch_bounds__(256, 3) void flash_kernel(
    const u16* __restrict__ Q,   // [32][2048][64], pre-scaled by 0.125*log2e
    const u16* __restrict__ K,   // [32][2048][64]
    const u16* __restrict__ V2,  // [32][128][64][16]
    u16* __restrict__ ctx)       // [4096][1024] = [b*2048+s][h*64+e]
{
    __shared__ __align__(16) char pool[34816];
    u16* stage = (u16*)pool;                              // K ring-3: 4w*3072 u16
    float (*Os)[64][66] = (float (*)[64][66])pool;        // merge (aliased)
    float (*Ls)[64] = (float (*)[64])(pool + 33792);      // 1 KB

    const int tid = threadIdx.x, lane = tid & 63, w = tid >> 6;
    const int c = lane & 15, qd = lane >> 4;
    const int bid = blockIdx.x;
    const int r5 = bid & 31;
    const int bh = (r5 & 7) * 4 + (r5 >> 3);   // pin each bh's blocks to one XCD
    const int q0 = (bid >> 5) * 64;
    const int b = bh >> 4, h = bh & 15;
    const u16* Qh = Q + (size_t)bh * 2048 * 64;
    const u16* Kh = K + (size_t)bh * 2048 * 64;
    const u16* Vh = V2 + (size_t)bh * 128 * 1024;

    u16* Kst = stage + w * 3072;             // 3 K slots x 1024 u16

    const int krow8 = lane >> 3;
    const int kgc = (lane & 7) ^ (krow8 & 7);
    const int voff = c * 16 + qd * 4;

    short8 qf[4][2];
    #pragma unroll
    for (int qb = 0; qb < 4; ++qb)
        #pragma unroll
        for (int kb = 0; kb < 2; ++kb)
            qf[qb][kb] = *(const short8*)&Qh[(size_t)(q0 + qb * 16 + c) * 64 + kb * 32 + qd * 8];

    f32x4 o[4][4];
    float lsum[4];
    #pragma unroll
    for (int mt = 0; mt < 4; ++mt)
        #pragma unroll
        for (int qb = 0; qb < 4; ++qb) o[mt][qb] = f32x4{0.f, 0.f, 0.f, 0.f};
    #pragma unroll
    for (int qb = 0; qb < 4; ++qb) lsum[qb] = 0.f;

    #pragma unroll
    for (int j = 0; j < 2; ++j) {
        const int row = j * 8 + krow8;
        gload_lds16(Kh + (size_t)(w * 512 + row) * 64 + kgc * 8,
                    Kst + j * 512 + lane * 8);
    }
    short4v vA[4], vB[4];
    {
        const u16* vb = Vh + (size_t)(w * 32) * 1024 + voff;
        #pragma unroll
        for (int mt = 0; mt < 4; ++mt)
            vA[mt] = *(const short4v*)(vb + mt * 256);
    }
    #pragma unroll
    for (int j = 0; j < 2; ++j) {
        const int row = j * 8 + krow8;
        gload_lds16(Kh + (size_t)(w * 512 + 16 + row) * 64 + kgc * 8,
                    Kst + 1024 + j * 512 + lane * 8);
    }

    int cur = 0;
    auto body = [&](int it, short4v (&VC)[4], short4v (&VN)[4]) {
        u16* Kb = Kst + cur * 1024;

        __builtin_amdgcn_s_waitcnt(0xF74);   // vmcnt(4): K(it) staged
        __builtin_amdgcn_sched_barrier(0);

        short8 kf[2];
        #pragma unroll
        for (int kb = 0; kb < 2; ++kb)
            kf[kb] = *(const short8*)&Kb[c * 64 + ((4 * kb + qd) ^ (c & 7)) * 8];

        __builtin_amdgcn_sched_barrier(0);

        {
            const int itn = (it + 1) & 31;
            const u16* vb = Vh + (size_t)(w * 32 + itn) * 1024 + voff;
            #pragma unroll
            for (int mt = 0; mt < 4; ++mt)
                VN[mt] = *(const short4v*)(vb + mt * 256);
        }
        {
            const int itn = (it + 2) & 31;
            const int t0n = w * 512 + itn * 16;
            const int nslot = (cur >= 1) ? cur - 1 : 2;
            u16* Kn = Kst + nslot * 1024;
            #pragma unroll
            for (int j = 0; j < 2; ++j) {
                const int row = j * 8 + krow8;
                gload_lds16(Kh + (size_t)(t0n + row) * 64 + kgc * 8,
                            Kn + j * 512 + lane * 8);
            }
        }

        f32x4 sc[4];
        #pragma unroll
        for (int qb = 0; qb < 4; ++qb) {
            sc[qb] = f32x4{0.f, 0.f, 0.f, 0.f};
            sc[qb] = __builtin_amdgcn_mfma_f32_16x16x32_bf16(kf[0], qf[qb][0], sc[qb], 0, 0, 0);
            sc[qb] = __builtin_amdgcn_mfma_f32_16x16x32_bf16(kf[1], qf[qb][1], sc[qb], 0, 0, 0);
        }

        short4v pb[4];
        #pragma unroll
        for (int qb = 0; qb < 4; ++qb) {
            float p0 = fexp2(sc[qb][0]);
            float p1 = fexp2(sc[qb][1]);
            float p2 = fexp2(sc[qb][2]);
            float p3 = fexp2(sc[qb][3]);
            lsum[qb] += (p0 + p1) + (p2 + p3);
            unsigned d0 = pack_bf16(p0, p1);
            unsigned d1 = pack_bf16(p2, p3);
            union { unsigned u[2]; short4v s; } pu;
            pu.u[0] = d0; pu.u[1] = d1;
            pb[qb] = pu.s;
        }

        #pragma unroll
        for (int qb = 0; qb < 4; ++qb)
            #pragma unroll
            for (int mt = 0; mt < 4; ++mt)
                o[mt][qb] = mfma16(VC[mt], pb[qb], o[mt][qb]);

        cur = (cur == 2) ? 0 : cur + 1;
    };

    for (int it2 = 0; it2 < 16; ++it2) {
        body(2 * it2, vA, vB);
        body(2 * it2 + 1, vB, vA);
    }

    __builtin_amdgcn_s_waitcnt(0xF70);   // vmcnt(0) before aliasing the pool
    __syncthreads();

    #pragma unroll
    for (int qb = 0; qb < 4; ++qb) {
        lsum[qb] += __shfl_xor(lsum[qb], 16, 64);
        lsum[qb] += __shfl_xor(lsum[qb], 32, 64);
    }
    if (qd == 0) {
        #pragma unroll
        for (int qb = 0; qb < 4; ++qb) Ls[w][qb * 16 + c] = lsum[qb];
    }

    if (w >= 2) {
        float (*S)[66] = Os[w - 2];
        #pragma unroll
        for (int mt = 0; mt < 4; ++mt)
            #pragma unroll
            for (int qb = 0; qb < 4; ++qb)
                #pragma unroll
                for (int r = 0; r < 4; ++r)
                    S[mt * 16 + qd * 4 + r][qb * 16 + c] = o[mt][qb][r];
    }
    __syncthreads();
    if (w < 2) {
        float (*S)[66] = Os[w];
        #pragma unroll
        for (int mt = 0; mt < 4; ++mt)
            #pragma unroll
            for (int qb = 0; qb < 4; ++qb)
                #pragma unroll
                for (int r = 0; r < 4; ++r)
                    o[mt][qb][r] += S[mt * 16 + qd * 4 + r][qb * 16 + c];
    }
    __syncthreads();
    if (w == 1) {
        float (*S)[66] = Os[0];
        #pragma unroll
        for (int mt = 0; mt < 4; ++mt)
            #pragma unroll
            for (int qb = 0; qb < 4; ++qb)
                #pragma unroll
                for (int r = 0; r < 4; ++r)
                    S[mt * 16 + qd * 4 + r][qb * 16 + c] = o[mt][qb][r];
    }
    __syncthreads();
    if (w == 0) {
        float (*S)[66] = Os[0];
        float inv[4];
        #pragma unroll
        for (int qb = 0; qb < 4; ++qb) {
            int q = qb * 16 + c;
            float l = (Ls[0][q] + Ls[1][q]) + (Ls[2][q] + Ls[3][q]);
            inv[qb] = __builtin_amdgcn_rcpf(l);
        }
        #pragma unroll
        for (int mt = 0; mt < 4; ++mt)
            #pragma unroll
            for (int qb = 0; qb < 4; ++qb) {
                u16x4 ov;
                #pragma unroll
                for (int r = 0; r < 4; ++r) {
                    float v = (o[mt][qb][r] + S[mt * 16 + qd * 4 + r][qb * 16 + c]) * inv[qb];
                    ((u16*)&ov)[r] = f2bf(v);
                }
                *(u16x4*)&ctx[((size_t)(b * 2048 + q0 + qb * 16 + c)) * 1024
                              + h * 64 + mt * 16 + qd * 4] = ov;
            }
    }
}

// ---------------- output projection: ctx[4096,1024] x Wo^T + bo, 64x128 tiles ----
__global__ __launch_bounds__(256, 4) void gemm_out_kernel(
    const u16* __restrict__ A, const u16* __restrict__ Wt,
    const float* __restrict__ bo, float* __restrict__ out)
{
    __shared__ __align__(16) u16 As[64 * 32];
    __shared__ __align__(16) u16 Bs[128 * 32];
    const int tid = threadIdx.x;
    const int lane = tid & 63;
    const int wv = tid >> 6;
    const int wm = wv & 1, wn = wv >> 1;
    const int m0 = blockIdx.x * 64;
    const int n0 = blockIdx.y * 128;
    const int c = lane & 15, qd = lane >> 4;

    f32x4 acc[2][4];
    #pragma unroll
    for (int a = 0; a < 2; ++a)
        #pragma unroll
        for (int b2 = 0; b2 < 4; ++b2) acc[a][b2] = f32x4{0.f, 0.f, 0.f, 0.f};

    const u16* Ab = A + (size_t)m0 * 1024;
    const u16* Wb = Wt + (size_t)n0 * 1024;

    for (int kt = 0; kt < 1024; kt += 32) {
        {
            int row = tid >> 2, part = tid & 3;
            gload_lds16(Ab + (size_t)row * 1024 + kt + part * 8, &As[tid * 8]);
        }
        #pragma unroll
        for (int i = 0; i < 2; ++i) {
            int slot = i * 256 + tid;
            int row = slot >> 2, part = slot & 3;
            gload_lds16(Wb + (size_t)row * 1024 + kt + part * 8, &Bs[slot * 8]);
        }
        __syncthreads();
        short8 af[2], bf[4];
        #pragma unroll
        for (int mt = 0; mt < 2; ++mt)
            af[mt] = *(const short8*)&As[(wm * 32 + mt * 16 + c) * 32 + qd * 8];
        #pragma unroll
        for (int nt = 0; nt < 4; ++nt)
            bf[nt] = *(const short8*)&Bs[(wn * 64 + nt * 16 + c) * 32 + qd * 8];
        #pragma unroll
        for (int mt = 0; mt < 2; ++mt)
            #pragma unroll
            for (int nt = 0; nt < 4; ++nt)
                acc[mt][nt] = __builtin_amdgcn_mfma_f32_16x16x32_bf16(af[mt], bf[nt], acc[mt][nt], 0, 0, 0);
        __syncthreads();
    }

    #pragma unroll
    for (int mt = 0; mt < 2; ++mt) {
        const int mbase = m0 + wm * 32 + mt * 16 + qd * 4;
        #pragma unroll
        for (int nt = 0; nt < 4; ++nt) {
            const int n = n0 + wn * 64 + nt * 16 + c;
            const float bias = bo[n];
            #pragma unroll
            for (int r = 0; r < 4; ++r)
                out[(size_t)(mbase + r) * 1024 + n] = acc[mt][nt][r] + bias;
        }
    }
}

extern "C" void kernel_launch(void* const* d_in, const int* in_sizes, int n_in,
                              void* d_out, int out_size, void* d_ws, size_t ws_size,
                              hipStream_t stream) {
    const float* x  = (const float*)d_in[0];
    const float* Wq = (const float*)d_in[1];
    const float* bq = (const float*)d_in[2];
    const float* Wk = (const float*)d_in[3];
    const float* bk = (const float*)d_in[4];
    const float* Wv = (const float*)d_in[5];
    const float* bv = (const float*)d_in[6];
    const float* Wo = (const float*)d_in[7];
    const float* bo = (const float*)d_in[8];
    float* out = (float*)d_out;

    u16* ws    = (u16*)d_ws;
    u16* xb    = ws;                          // 4096*1024
    u16* wqkv  = xb + 4096 * 1024;            // 3072*1024
    u16* wot   = wqkv + 3072 * 1024;          // 1024*1024
    u16* qws   = wot + 1024 * 1024;           // 32*2048*64
    u16* kws   = qws + 4194304;               // 32*2048*64
    u16* v2ws  = kws + 4194304;               // 32*128*64*16
    u16* ctxws = v2ws + 4194304;              // 4096*1024

    prep_kernel<<<dim3(16, 16, 5), 256, 0, stream>>>(x, Wq, Wk, Wv, Wo, xb, wqkv, wot);
    gemm_qkv_kernel<<<256, 512, 0, stream>>>(xb, wqkv, bq, bk, bv, qws, kws, v2ws);
    flash_kernel<<<1024, 256, 0, stream>>>(qws, kws, v2ws, ctxws);
    gemm_out_kernel<<<dim3(64, 8), 256, 0, stream>>>(ctxws, wot, bo, out);
}

// Round 9
// 186.929 us; speedup vs baseline: 1.1493x; 1.0093x over previous
//
#include <hip/hip_runtime.h>
#include <cstdint>

typedef unsigned short u16;
typedef __attribute__((ext_vector_type(8))) short short8;
typedef __attribute__((ext_vector_type(4))) short short4v;
typedef __attribute__((ext_vector_type(4))) float f32x4;
typedef __attribute__((ext_vector_type(4))) unsigned short u16x4;

__device__ __forceinline__ u16 f2bf(float x) {
    unsigned int u = __float_as_uint(x);
    u += 0x7fffu + ((u >> 16) & 1u);
    return (u16)(u >> 16);
}

__device__ __forceinline__ float fexp2(float x) {
#if __has_builtin(__builtin_amdgcn_exp2f)
    return __builtin_amdgcn_exp2f(x);
#else
    return exp2f(x);
#endif
}

// pack two rounded f32 -> bf16 pair in one dword (a low16, b high16) — proven path
__device__ __forceinline__ unsigned pack_bf16(float a, float b) {
    unsigned ua = __float_as_uint(a) + 0x8000u;
    unsigned ub = __float_as_uint(b) + 0x8000u;
    return __builtin_amdgcn_perm(ub, ua, 0x07060302u);
}

#if __has_builtin(__builtin_amdgcn_mfma_f32_16x16x16bf16_1k)
__device__ __forceinline__ f32x4 mfma16(short4v a, short4v b, f32x4 c) {
    return __builtin_amdgcn_mfma_f32_16x16x16bf16_1k(a, b, c, 0, 0, 0);
}
#else
__device__ __forceinline__ f32x4 mfma16(short4v a, short4v b, f32x4 c) {
    short8 a8 = {a[0], a[1], a[2], a[3], 0, 0, 0, 0};
    short8 b8 = {b[0], b[1], b[2], b[3], 0, 0, 0, 0};
    return __builtin_amdgcn_mfma_f32_16x16x32_bf16(a8, b8, c, 0, 0, 0);
}
#endif

__device__ __forceinline__ void gload_lds16(const u16* g, u16* l) {
    __builtin_amdgcn_global_load_lds(
        (const __attribute__((address_space(1))) void*)(g),
        (__attribute__((address_space(3))) void*)(l),
        16, 0, 0);
}

#define SBAR() do { __builtin_amdgcn_sched_barrier(0); \
                    __builtin_amdgcn_s_barrier(); \
                    __builtin_amdgcn_sched_barrier(0); } while (0)

// ---------------- fused prep: Wo transpose | cast x | Wq/Wk/Wv transposes ------
__global__ __launch_bounds__(256) void prep_kernel(
    const float* __restrict__ x,
    const float* __restrict__ Wq, const float* __restrict__ Wk,
    const float* __restrict__ Wv, const float* __restrict__ Wo,
    u16* __restrict__ xb, u16* __restrict__ wqkv, u16* __restrict__ wot)
{
    __shared__ u16 tile[64][65];
    const int z = blockIdx.z;
    const int tc = threadIdx.x & 63, tr = threadIdx.x >> 6;

    if (z == 1) {
        const int blk = blockIdx.y * 16 + blockIdx.x;
        const int base = (blk * 256 + threadIdx.x) * 4;
        #pragma unroll
        for (int i = 0; i < 16; ++i) {
            const int idx = base + i * 262144;
            float4 v = *(const float4*)(x + idx);
            u16x4 o;
            o.x = f2bf(v.x); o.y = f2bf(v.y); o.z = f2bf(v.z); o.w = f2bf(v.w);
            *(u16x4*)(xb + idx) = o;
        }
        return;
    }

    const float* src;
    u16* dst;
    int C, R, rb, cb;
    if (z == 0) {
        src = Wo; dst = wot; C = 1024; R = 1024;
        rb = blockIdx.x * 64; cb = blockIdx.y * 64;
    } else {
        const float* W = (z == 2) ? Wq : (z == 3) ? Wk : Wv;
        const int head = blockIdx.y;
        src = W + head * 65536;                                  // [1024][64]
        dst = wqkv + (size_t)(z - 2) * 1048576 + head * 65536;   // rows e, cols d
        C = 64; R = 1024;
        rb = blockIdx.x * 64; cb = 0;
    }
    #pragma unroll
    for (int i = 0; i < 64; i += 4)
        tile[tr + i][tc] = f2bf(src[(size_t)(rb + tr + i) * C + (cb + tc)]);
    __syncthreads();
    #pragma unroll
    for (int i = 0; i < 64; i += 4)
        dst[(size_t)(cb + tr + i) * R + (rb + tc)] = tile[tc][tr + i];
}

// ---------------- QKV GEMM v4: 256x192 tile, BK=64, 3-phase, 256 blocks -------
// (R8-proven verbatim: 188.7 us total, -2 vs 128^2 baseline)
__global__ __launch_bounds__(512, 2) void gemm_qkv_kernel(
    const u16* __restrict__ X, const u16* __restrict__ W,
    const float* __restrict__ bq, const float* __restrict__ bk,
    const float* __restrict__ bv,
    u16* __restrict__ qo, u16* __restrict__ ko, u16* __restrict__ vto)
{
    __shared__ __align__(16) u16 lds[57344];   // 112 KiB: 2 x [A 16384 | B 12288]
    const int tid = threadIdx.x;
    const int lane = tid & 63;
    const int wid = tid >> 6;            // 0..7
    const int wm = wid >> 2;             // 0..1  (128-row half)
    const int wn = wid & 3;              // 0..3  (48-col quarter)
    const int c = lane & 15, qd = lane >> 4;

    const int grp = blockIdx.x & 7, k = blockIdx.x >> 3;
    const int m0 = ((grp >> 1) * 4 + (k >> 3)) * 256;
    const int n0 = ((grp & 1) * 8 + (k & 7)) * 192;
    const u16* Xb = X + (size_t)m0 * 1024;
    const u16* Wb = W + (size_t)n0 * 1024;

    const int scg  = (tid & 7) ^ ((tid >> 3) & 7);  // staging source chunk
    const int srow = tid >> 3;                      // row within 64-row quarter
    const int co0 = (qd ^ (c & 7)) * 8;             // read chunk offset, ks=0
    const int co1 = ((4 + qd) ^ (c & 7)) * 8;       // ks=1
    const int rA = wm * 128 + c;
    const int rB = wn * 48 + c;

    auto stageA = [&](int t, int qa) {
        const int pb = (t & 1) * 28672;
        gload_lds16(Xb + (size_t)(qa * 64 + srow) * 1024 + t * 64 + scg * 8,
                    &lds[pb + (qa * 512 + tid) * 8]);
    };
    auto stageB = [&](int t, int qb) {
        const int pb = (t & 1) * 28672;
        gload_lds16(Wb + (size_t)(qb * 64 + srow) * 1024 + t * 64 + scg * 8,
                    &lds[pb + 16384 + (qb * 512 + tid) * 8]);
    };

    f32x4 acc[8][3];
    #pragma unroll
    for (int mi = 0; mi < 8; ++mi)
        #pragma unroll
        for (int ni = 0; ni < 3; ++ni) acc[mi][ni] = f32x4{0.f, 0.f, 0.f, 0.f};

    #pragma unroll
    for (int q = 0; q < 4; ++q) stageA(0, q);
    #pragma unroll
    for (int q = 0; q < 3; ++q) stageB(0, q);
    #pragma unroll
    for (int q = 0; q < 4; ++q) stageA(1, q);
    #pragma unroll
    for (int q = 0; q < 3; ++q) stageB(1, q);
    __builtin_amdgcn_s_waitcnt(0xF77);   // vmcnt(7): tile 0's 7 landed
    SBAR();

    #pragma unroll 2
    for (int t = 0; t < 16; ++t) {
        const int pb = (t & 1) * 28672;
        const u16* Al = &lds[pb];
        const u16* Bl = &lds[pb + 16384];

        // ---- Phase 1
        short8 af0[4][2], bf[3][2];
        #pragma unroll
        for (int mi = 0; mi < 4; ++mi) {
            af0[mi][0] = *(const short8*)&Al[(rA + mi * 16) * 64 + co0];
            af0[mi][1] = *(const short8*)&Al[(rA + mi * 16) * 64 + co1];
        }
        #pragma unroll
        for (int ni = 0; ni < 2; ++ni) {
            bf[ni][0] = *(const short8*)&Bl[(rB + ni * 16) * 64 + co0];
            bf[ni][1] = *(const short8*)&Bl[(rB + ni * 16) * 64 + co1];
        }
        SBAR();
        __builtin_amdgcn_s_setprio(1);
        #pragma unroll
        for (int mi = 0; mi < 4; ++mi)
            #pragma unroll
            for (int ni = 0; ni < 2; ++ni) {
                acc[mi][ni] = __builtin_amdgcn_mfma_f32_16x16x32_bf16(af0[mi][0], bf[ni][0], acc[mi][ni], 0, 0, 0);
                acc[mi][ni] = __builtin_amdgcn_mfma_f32_16x16x32_bf16(af0[mi][1], bf[ni][1], acc[mi][ni], 0, 0, 0);
            }
        __builtin_amdgcn_s_setprio(0);
        SBAR();

        // ---- Phase 2
        short8 af1[4][2];
        #pragma unroll
        for (int mi = 0; mi < 4; ++mi) {
            af1[mi][0] = *(const short8*)&Al[(rA + (mi + 4) * 16) * 64 + co0];
            af1[mi][1] = *(const short8*)&Al[(rA + (mi + 4) * 16) * 64 + co1];
        }
        bf[2][0] = *(const short8*)&Bl[(rB + 2 * 16) * 64 + co0];
        bf[2][1] = *(const short8*)&Bl[(rB + 2 * 16) * 64 + co1];
        if (t < 14) { stageA(t + 2, 0); stageA(t + 2, 2); }
        SBAR();
        __builtin_amdgcn_s_setprio(1);
        #pragma unroll
        for (int mi = 0; mi < 4; ++mi) {
            acc[mi][2] = __builtin_amdgcn_mfma_f32_16x16x32_bf16(af0[mi][0], bf[2][0], acc[mi][2], 0, 0, 0);
            acc[mi][2] = __builtin_amdgcn_mfma_f32_16x16x32_bf16(af0[mi][1], bf[2][1], acc[mi][2], 0, 0, 0);
        }
        #pragma unroll
        for (int mi = 0; mi < 4; ++mi) {
            acc[mi + 4][0] = __builtin_amdgcn_mfma_f32_16x16x32_bf16(af1[mi][0], bf[0][0], acc[mi + 4][0], 0, 0, 0);
            acc[mi + 4][0] = __builtin_amdgcn_mfma_f32_16x16x32_bf16(af1[mi][1], bf[0][1], acc[mi + 4][0], 0, 0, 0);
        }
        __builtin_amdgcn_s_setprio(0);
        SBAR();

        // ---- Phase 3
        if (t < 14) {
            stageA(t + 2, 1); stageA(t + 2, 3);
            stageB(t + 2, 0); stageB(t + 2, 1); stageB(t + 2, 2);
        }
        SBAR();
        __builtin_amdgcn_s_setprio(1);
        #pragma unroll
        for (int mi = 0; mi < 4; ++mi)
            #pragma unroll
            for (int ni = 1; ni < 3; ++ni) {
                acc[mi + 4][ni] = __builtin_amdgcn_mfma_f32_16x16x32_bf16(af1[mi][0], bf[ni][0], acc[mi + 4][ni], 0, 0, 0);
                acc[mi + 4][ni] = __builtin_amdgcn_mfma_f32_16x16x32_bf16(af1[mi][1], bf[ni][1], acc[mi + 4][ni], 0, 0, 0);
            }
        __builtin_amdgcn_s_setprio(0);
        if (t < 14)       __builtin_amdgcn_s_waitcnt(0xF77);   // vmcnt(7)
        else if (t == 14) __builtin_amdgcn_s_waitcnt(0xF70);   // vmcnt(0): last
        SBAR();
    }

    // epilogue: n -> (mat, h, e); m -> (b, s)
    #pragma unroll
    for (int mi = 0; mi < 8; ++mi) {
        const int mbase = m0 + wm * 128 + mi * 16 + qd * 4;
        const int b = mbase >> 11;
        #pragma unroll
        for (int ni = 0; ni < 3; ++ni) {
            const int n = n0 + wn * 48 + ni * 16 + c;
            const int mat = n >> 10;
            const int idx = n & 1023;
            const int h = idx >> 6, e = idx & 63;
            const float bias = (mat == 0 ? bq : (mat == 1 ? bk : bv))[idx];
            if (mat == 2) {
                const int s = mbase & 2047;
                u16x4 pv;
                pv.x = f2bf(acc[mi][ni][0] + bias);
                pv.y = f2bf(acc[mi][ni][1] + bias);
                pv.z = f2bf(acc[mi][ni][2] + bias);
                pv.w = f2bf(acc[mi][ni][3] + bias);
                *(u16x4*)(vto + ((((size_t)(b * 16 + h) * 128 + (s >> 4)) * 64 + e) * 16
                                 + (s & 15))) = pv;
            } else {
                const float scale = (mat == 0) ? 0.18033688011112042f : 1.0f;
                u16* dst = (mat == 0) ? qo : ko;
                #pragma unroll
                for (int r = 0; r < 4; ++r) {
                    const int s = (mbase + r) & 2047;
                    dst[((size_t)((b * 16 + h) * 2048 + s)) * 64 + e] =
                        f2bf((acc[mi][ni][r] + bias) * scale);
                }
            }
        }
    }
}

// ---------------- flash attention v8 (proven 53.4-54.6 us, verbatim) ----------
__global__ __launch_bounds__(256, 3) void flash_kernel(
    const u16* __restrict__ Q,   // [32][2048][64], pre-scaled by 0.125*log2e
    const u16* __restrict__ K,   // [32][2048][64]
    const u16* __restrict__ V2,  // [32][128][64][16]
    u16* __restrict__ ctx)       // [4096][1024] = [b*2048+s][h*64+e]
{
    __shared__ __align__(16) char pool[34816];
    u16* stage = (u16*)pool;                              // K ring-3: 4w*3072 u16
    float (*Os)[64][66] = (float (*)[64][66])pool;        // merge (aliased)
    float (*Ls)[64] = (float (*)[64])(pool + 33792);      // 1 KB

    const int tid = threadIdx.x, lane = tid & 63, w = tid >> 6;
    const int c = lane & 15, qd = lane >> 4;
    const int bid = blockIdx.x;
    const int r5 = bid & 31;
    const int bh = (r5 & 7) * 4 + (r5 >> 3);   // pin each bh's blocks to one XCD
    const int q0 = (bid >> 5) * 64;
    const int b = bh >> 4, h = bh & 15;
    const u16* Qh = Q + (size_t)bh * 2048 * 64;
    const u16* Kh = K + (size_t)bh * 2048 * 64;
    const u16* Vh = V2 + (size_t)bh * 128 * 1024;

    u16* Kst = stage + w * 3072;             // 3 K slots x 1024 u16

    const int krow8 = lane >> 3;
    const int kgc = (lane & 7) ^ (krow8 & 7);
    const int voff = c * 16 + qd * 4;

    short8 qf[4][2];
    #pragma unroll
    for (int qb = 0; qb < 4; ++qb)
        #pragma unroll
        for (int kb = 0; kb < 2; ++kb)
            qf[qb][kb] = *(const short8*)&Qh[(size_t)(q0 + qb * 16 + c) * 64 + kb * 32 + qd * 8];

    f32x4 o[4][4];
    float lsum[4];
    #pragma unroll
    for (int mt = 0; mt < 4; ++mt)
        #pragma unroll
        for (int qb = 0; qb < 4; ++qb) o[mt][qb] = f32x4{0.f, 0.f, 0.f, 0.f};
    #pragma unroll
    for (int qb = 0; qb < 4; ++qb) lsum[qb] = 0.f;

    #pragma unroll
    for (int j = 0; j < 2; ++j) {
        const int row = j * 8 + krow8;
        gload_lds16(Kh + (size_t)(w * 512 + row) * 64 + kgc * 8,
                    Kst + j * 512 + lane * 8);
    }
    short4v vA[4], vB[4];
    {
        const u16* vb = Vh + (size_t)(w * 32) * 1024 + voff;
        #pragma unroll
        for (int mt = 0; mt < 4; ++mt)
            vA[mt] = *(const short4v*)(vb + mt * 256);
    }
    #pragma unroll
    for (int j = 0; j < 2; ++j) {
        const int row = j * 8 + krow8;
        gload_lds16(Kh + (size_t)(w * 512 + 16 + row) * 64 + kgc * 8,
                    Kst + 1024 + j * 512 + lane * 8);
    }

    int cur = 0;
    auto body = [&](int it, short4v (&VC)[4], short4v (&VN)[4]) {
        u16* Kb = Kst + cur * 1024;

        __builtin_amdgcn_s_waitcnt(0xF74);   // vmcnt(4): K(it) staged
        __builtin_amdgcn_sched_barrier(0);

        short8 kf[2];
        #pragma unroll
        for (int kb = 0; kb < 2; ++kb)
            kf[kb] = *(const short8*)&Kb[c * 64 + ((4 * kb + qd) ^ (c & 7)) * 8];

        __builtin_amdgcn_sched_barrier(0);

        {
            const int itn = (it + 1) & 31;
            const u16* vb = Vh + (size_t)(w * 32 + itn) * 1024 + voff;
            #pragma unroll
            for (int mt = 0; mt < 4; ++mt)
                VN[mt] = *(const short4v*)(vb + mt * 256);
        }
        {
            const int itn = (it + 2) & 31;
            const int t0n = w * 512 + itn * 16;
            const int nslot = (cur >= 1) ? cur - 1 : 2;
            u16* Kn = Kst + nslot * 1024;
            #pragma unroll
            for (int j = 0; j < 2; ++j) {
                const int row = j * 8 + krow8;
                gload_lds16(Kh + (size_t)(t0n + row) * 64 + kgc * 8,
                            Kn + j * 512 + lane * 8);
            }
        }

        f32x4 sc[4];
        #pragma unroll
        for (int qb = 0; qb < 4; ++qb) {
            sc[qb] = f32x4{0.f, 0.f, 0.f, 0.f};
            sc[qb] = __builtin_amdgcn_mfma_f32_16x16x32_bf16(kf[0], qf[qb][0], sc[qb], 0, 0, 0);
            sc[qb] = __builtin_amdgcn_mfma_f32_16x16x32_bf16(kf[1], qf[qb][1], sc[qb], 0, 0, 0);
        }

        short4v pb[4];
        #pragma unroll
        for (int qb = 0; qb < 4; ++qb) {
            float p0 = fexp2(sc[qb][0]);
            float p1 = fexp2(sc[qb][1]);
            float p2 = fexp2(sc[qb][2]);
            float p3 = fexp2(sc[qb][3]);
            lsum[qb] += (p0 + p1) + (p2 + p3);
            unsigned d0 = pack_bf16(p0, p1);
            unsigned d1 = pack_bf16(p2, p3);
            union { unsigned u[2]; short4v s; } pu;
            pu.u[0] = d0; pu.u[1] = d1;
            pb[qb] = pu.s;
        }

        #pragma unroll
        for (int qb = 0; qb < 4; ++qb)
            #pragma unroll
            for (int mt = 0; mt < 4; ++mt)
                o[mt][qb] = mfma16(VC[mt], pb[qb], o[mt][qb]);

        cur = (cur == 2) ? 0 : cur + 1;
    };

    for (int it2 = 0; it2 < 16; ++it2) {
        body(2 * it2, vA, vB);
        body(2 * it2 + 1, vB, vA);
    }

    __builtin_amdgcn_s_waitcnt(0xF70);   // vmcnt(0) before aliasing the pool
    __syncthreads();

    #pragma unroll
    for (int qb = 0; qb < 4; ++qb) {
        lsum[qb] += __shfl_xor(lsum[qb], 16, 64);
        lsum[qb] += __shfl_xor(lsum[qb], 32, 64);
    }
    if (qd == 0) {
        #pragma unroll
        for (int qb = 0; qb < 4; ++qb) Ls[w][qb * 16 + c] = lsum[qb];
    }

    if (w >= 2) {
        float (*S)[66] = Os[w - 2];
        #pragma unroll
        for (int mt = 0; mt < 4; ++mt)
            #pragma unroll
            for (int qb = 0; qb < 4; ++qb)
                #pragma unroll
                for (int r = 0; r < 4; ++r)
                    S[mt * 16 + qd * 4 + r][qb * 16 + c] = o[mt][qb][r];
    }
    __syncthreads();
    if (w < 2) {
        float (*S)[66] = Os[w];
        #pragma unroll
        for (int mt = 0; mt < 4; ++mt)
            #pragma unroll
            for (int qb = 0; qb < 4; ++qb)
                #pragma unroll
                for (int r = 0; r < 4; ++r)
                    o[mt][qb][r] += S[mt * 16 + qd * 4 + r][qb * 16 + c];
    }
    __syncthreads();
    if (w == 1) {
        float (*S)[66] = Os[0];
        #pragma unroll
        for (int mt = 0; mt < 4; ++mt)
            #pragma unroll
            for (int qb = 0; qb < 4; ++qb)
                #pragma unroll
                for (int r = 0; r < 4; ++r)
                    S[mt * 16 + qd * 4 + r][qb * 16 + c] = o[mt][qb][r];
    }
    __syncthreads();
    if (w == 0) {
        float (*S)[66] = Os[0];
        float inv[4];
        #pragma unroll
        for (int qb = 0; qb < 4; ++qb) {
            int q = qb * 16 + c;
            float l = (Ls[0][q] + Ls[1][q]) + (Ls[2][q] + Ls[3][q]);
            inv[qb] = __builtin_amdgcn_rcpf(l);
        }
        #pragma unroll
        for (int mt = 0; mt < 4; ++mt)
            #pragma unroll
            for (int qb = 0; qb < 4; ++qb) {
                u16x4 ov;
                #pragma unroll
                for (int r = 0; r < 4; ++r) {
                    float v = (o[mt][qb][r] + S[mt * 16 + qd * 4 + r][qb * 16 + c]) * inv[qb];
                    ((u16*)&ov)[r] = f2bf(v);
                }
                *(u16x4*)&ctx[((size_t)(b * 2048 + q0 + qb * 16 + c)) * 1024
                              + h * 64 + mt * 16 + qd * 4] = ov;
            }
    }
}

// ---------------- output projection v2: 64x128 tile, double-buffered pipeline --
// Same tile/epilogue as proven v1; adds the R7/R8-proven pipeline discipline:
//  * 2x LDS buffers (24 KB total, 4 blocks/CU retained).
//  * stage(t+1) issued at iter-t top -> queue [t(3) oldest, t+1(3)];
//    gate vmcnt(3), NEVER 0 until t=31 (kills the per-K-step
//    __syncthreads vmcnt(0) drain = the documented ~20% structural stall).
//  * raw s_barrier + sched_barrier fences; every ds_read is MFMA-consumed
//    before the closing barrier (same hazard discipline as qkv/flash).
//  * XCD-swizzled 1-D grid (512 = 8 XCD x 64): each XCD's blocks share
//    8 A-panels (1 MB) + full B (2 MB) ~ L2-sized.
__global__ __launch_bounds__(256, 4) void gemm_out_kernel(
    const u16* __restrict__ A, const u16* __restrict__ Wt,
    const float* __restrict__ bo, float* __restrict__ out)
{
    __shared__ __align__(16) u16 As[2][64 * 32];
    __shared__ __align__(16) u16 Bs[2][128 * 32];
    const int tid = threadIdx.x;
    const int lane = tid & 63;
    const int wv = tid >> 6;
    const int wm = wv & 1, wn = wv >> 1;
    const int c = lane & 15, qd = lane >> 4;

    // XCD swizzle: 512 = 8 x 64; id -> (m-tile, n-tile)
    const int id = (blockIdx.x & 7) * 64 + (blockIdx.x >> 3);
    const int m0 = (id >> 3) * 64;
    const int n0 = (id & 7) * 128;

    f32x4 acc[2][4];
    #pragma unroll
    for (int a = 0; a < 2; ++a)
        #pragma unroll
        for (int b2 = 0; b2 < 4; ++b2) acc[a][b2] = f32x4{0.f, 0.f, 0.f, 0.f};

    const u16* Ab = A + (size_t)m0 * 1024;
    const u16* Wb = Wt + (size_t)n0 * 1024;

    const int arow = tid >> 2, apart = tid & 3;

    auto stage = [&](int t, int p) {
        gload_lds16(Ab + (size_t)arow * 1024 + t * 32 + apart * 8, &As[p][tid * 8]);
        #pragma unroll
        for (int i = 0; i < 2; ++i) {
            int slot = i * 256 + tid;
            int row = slot >> 2, part = slot & 3;
            gload_lds16(Wb + (size_t)row * 1024 + t * 32 + part * 8, &Bs[p][slot * 8]);
        }
    };

    stage(0, 0);

    for (int t = 0; t < 32; ++t) {
        const int p = t & 1;
        if (t < 31) stage(t + 1, p ^ 1);
        __builtin_amdgcn_sched_barrier(0);
        if (t < 31) __builtin_amdgcn_s_waitcnt(0xF73);   // vmcnt(3): tile t landed
        else        __builtin_amdgcn_s_waitcnt(0xF70);   // last tile: drain
        SBAR();
        short8 af[2], bf[4];
        #pragma unroll
        for (int mt = 0; mt < 2; ++mt)
            af[mt] = *(const short8*)&As[p][(wm * 32 + mt * 16 + c) * 32 + qd * 8];
        #pragma unroll
        for (int nt = 0; nt < 4; ++nt)
            bf[nt] = *(const short8*)&Bs[p][(wn * 64 + nt * 16 + c) * 32 + qd * 8];
        __builtin_amdgcn_s_setprio(1);
        #pragma unroll
        for (int mt = 0; mt < 2; ++mt)
            #pragma unroll
            for (int nt = 0; nt < 4; ++nt)
                acc[mt][nt] = __builtin_amdgcn_mfma_f32_16x16x32_bf16(af[mt], bf[nt], acc[mt][nt], 0, 0, 0);
        __builtin_amdgcn_s_setprio(0);
        SBAR();   // all reads of buf p done before it is re-staged at t+2
    }

    #pragma unroll
    for (int mt = 0; mt < 2; ++mt) {
        const int mbase = m0 + wm * 32 + mt * 16 + qd * 4;
        #pragma unroll
        for (int nt = 0; nt < 4; ++nt) {
            const int n = n0 + wn * 64 + nt * 16 + c;
            const float bias = bo[n];
            #pragma unroll
            for (int r = 0; r < 4; ++r)
                out[(size_t)(mbase + r) * 1024 + n] = acc[mt][nt][r] + bias;
        }
    }
}

extern "C" void kernel_launch(void* const* d_in, const int* in_sizes, int n_in,
                              void* d_out, int out_size, void* d_ws, size_t ws_size,
                              hipStream_t stream) {
    const float* x  = (const float*)d_in[0];
    const float* Wq = (const float*)d_in[1];
    const float* bq = (const float*)d_in[2];
    const float* Wk = (const float*)d_in[3];
    const float* bk = (const float*)d_in[4];
    const float* Wv = (const float*)d_in[5];
    const float* bv = (const float*)d_in[6];
    const float* Wo = (const float*)d_in[7];
    const float* bo = (const float*)d_in[8];
    float* out = (float*)d_out;

    u16* ws    = (u16*)d_ws;
    u16* xb    = ws;                          // 4096*1024
    u16* wqkv  = xb + 4096 * 1024;            // 3072*1024
    u16* wot   = wqkv + 3072 * 1024;          // 1024*1024
    u16* qws   = wot + 1024 * 1024;           // 32*2048*64
    u16* kws   = qws + 4194304;               // 32*2048*64
    u16* v2ws  = kws + 4194304;               // 32*128*64*16
    u16* ctxws = v2ws + 4194304;              // 4096*1024

    prep_kernel<<<dim3(16, 16, 5), 256, 0, stream>>>(x, Wq, Wk, Wv, Wo, xb, wqkv, wot);
    gemm_qkv_kernel<<<256, 512, 0, stream>>>(xb, wqkv, bq, bk, bv, qws, kws, v2ws);
    flash_kernel<<<1024, 256, 0, stream>>>(qws, kws, v2ws, ctxws);
    gemm_out_kernel<<<512, 256, 0, stream>>>(ctxws, wot, bo, out);
}